// Round 3
// baseline (3392.231 us; speedup 1.0000x reference)
//
#include <hip/hip_runtime.h>
#include <hip/hip_bf16.h>

#define NN    50000
#define RR    8
#define HIDC  128
#define NHEADS 4
#define EE    640000
#define EE2   200000
#define NCL   8

typedef __hip_bfloat16 bf16;
typedef unsigned short u16;

__device__ __forceinline__ float us2f(u16 u) {
    return __uint_as_float(((unsigned)u) << 16);
}
__device__ __forceinline__ float bf2f(bf16 v) { return __bfloat162float(v); }
__device__ __forceinline__ u16 f2us(float f) {
    bf16 h = __float2bfloat16(f);
    return *(u16*)&h;
}
// dual-dtype scalar load: f32 flag picks interpretation
__device__ __forceinline__ float ldf(const void* p, int i, bool f32) {
    return f32 ? ((const float*)p)[i] : us2f(((const u16*)p)[i]);
}

// monotonic float->uint key for atomicMax-based segment_max
__device__ __forceinline__ unsigned fkey(float f) {
    unsigned u = __float_as_uint(f);
    return (u & 0x80000000u) ? ~u : (u | 0x80000000u);
}

// ---------------- dtype sniff: fp32 data viewed as bf16 has exp==0xFF hits ----------------
__global__ void k_sniff(const u16* __restrict__ x, int* __restrict__ flags) {
    __shared__ int cnt;
    if (threadIdx.x == 0) cnt = 0;
    __syncthreads();
    int c = 0;
    for (int i = threadIdx.x; i < 262144; i += 256)
        if (((x[i] >> 7) & 0xFF) == 0xFF) c++;
    atomicAdd(&cnt, c);
    __syncthreads();
    if (threadIdx.x == 0) { flags[0] = (cnt > 32) ? 1 : 0; flags[1] = 1; }
}

// ---------------- init: acc=0, den=0, amax=key(-inf) ----------------
__global__ void k_init(unsigned* __restrict__ amaxK, float* __restrict__ den,
                       float* __restrict__ acc) {
    int i = blockIdx.x * 256 + threadIdx.x;
    if (i < NN * HIDC) acc[i] = 0.f;
    if (i < NN * NHEADS) { amaxK[i] = 0x007FFFFFu; den[i] = 0.f; }
}

// ---------------- xw[n,r,:] = X[n,:] @ W[r]  (bf16 out) ----------------
__global__ __launch_bounds__(256) void k_xw(const void* __restrict__ X,
                                            const void* __restrict__ W,
                                            bf16* __restrict__ xw,
                                            const int* __restrict__ fx,
                                            const int* __restrict__ fw) {
    __shared__ u16 WsU[HIDC * HIDC];   // 32 KB
    __shared__ float Xs[32][HIDC];     // 16 KB
    const int tid = threadIdx.x;
    const int r = blockIdx.y;
    const int n0 = blockIdx.x * 32;
    const bool xf = fx[0] != 0, wf = fw[0] != 0;
    if (wf) {
        const float* Wr = (const float*)W + r * HIDC * HIDC;
        for (int v = tid; v < HIDC * HIDC / 4; v += 256) {
            float4 w4 = ((const float4*)Wr)[v];
            ushort4 o = {f2us(w4.x), f2us(w4.y), f2us(w4.z), f2us(w4.w)};
            ((ushort4*)WsU)[v] = o;
        }
    } else {
        const u16* Wr = (const u16*)W + r * HIDC * HIDC;
        for (int v = tid; v < HIDC * HIDC / 4; v += 256)
            ((ushort4*)WsU)[v] = ((const ushort4*)Wr)[v];
    }
    for (int v = tid; v < 32 * HIDC / 4; v += 256) {
        int row = v >> 5, c = (v & 31) * 4, n = n0 + row;
        float4 val = {0.f, 0.f, 0.f, 0.f};
        if (n < NN) {
            if (xf) val = *(const float4*)((const float*)X + (size_t)n * HIDC + c);
            else {
                ushort4 u = *(const ushort4*)((const u16*)X + (size_t)n * HIDC + c);
                val = float4{us2f(u.x), us2f(u.y), us2f(u.z), us2f(u.w)};
            }
        }
        *(float4*)&Xs[row][c] = val;
    }
    __syncthreads();
    const int to = (tid & 31) * 4;   // output col base (4 cols)
    const int tn = (tid >> 5) * 4;   // node base within tile (4 nodes)
    float acc[4][4] = {};
    for (int i = 0; i < HIDC; i += 4) {
        float4 xv[4], wv[4];
#pragma unroll
        for (int a = 0; a < 4; a++) xv[a] = *(const float4*)&Xs[tn + a][i];
#pragma unroll
        for (int b = 0; b < 4; b++) {
            ushort4 wu = *(const ushort4*)&WsU[(i + b) * HIDC + to];
            wv[b] = float4{us2f(wu.x), us2f(wu.y), us2f(wu.z), us2f(wu.w)};
        }
#pragma unroll
        for (int a = 0; a < 4; a++) {
            float4 xa = xv[a];
            acc[a][0] += xa.x * wv[0].x + xa.y * wv[1].x + xa.z * wv[2].x + xa.w * wv[3].x;
            acc[a][1] += xa.x * wv[0].y + xa.y * wv[1].y + xa.z * wv[2].y + xa.w * wv[3].y;
            acc[a][2] += xa.x * wv[0].z + xa.y * wv[1].z + xa.z * wv[2].z + xa.w * wv[3].z;
            acc[a][3] += xa.x * wv[0].w + xa.y * wv[1].w + xa.z * wv[2].w + xa.w * wv[3].w;
        }
    }
#pragma unroll
    for (int a = 0; a < 4; a++) {
        int n = n0 + tn + a;
        if (n < NN) {
            ushort4 o = {f2us(acc[a][0]), f2us(acc[a][1]), f2us(acc[a][2]), f2us(acc[a][3])};
            *(ushort4*)((u16*)xw + (size_t)(n * RR + r) * HIDC + to) = o;
        }
    }
}

// ---------------- s[n,r,h]=xw[n,r,:]@q[:,h]; t likewise with k ----------------
__global__ __launch_bounds__(256) void k_st(const bf16* __restrict__ xw,
                                            const void* __restrict__ q,
                                            const void* __restrict__ k,
                                            float* __restrict__ s, float* __restrict__ t,
                                            const int* __restrict__ fl) {
    __shared__ float qs[NHEADS * HIDC];
    __shared__ float ks[NHEADS * HIDC];
    const bool f = fl[0] != 0;
    for (int v = threadIdx.x; v < HIDC * NHEADS; v += 256) {
        int hh = v & 3; int i = v >> 2;           // q layout [i][h]
        qs[hh * HIDC + i] = ldf(q, v, f);
        ks[hh * HIDC + i] = ldf(k, v, f);
    }
    __syncthreads();
    int lane = threadIdx.x & 63;
    int row = blockIdx.x * 4 + (threadIdx.x >> 6);
    if (row >= NN * RR) return;
    const bf16* xr = xw + (size_t)row * HIDC;
    float v0 = bf2f(xr[lane]), v1 = bf2f(xr[lane + 64]);
    float sv[NHEADS], tv[NHEADS];
#pragma unroll
    for (int h = 0; h < NHEADS; h++) {
        sv[h] = v0 * qs[h * HIDC + lane] + v1 * qs[h * HIDC + 64 + lane];
        tv[h] = v0 * ks[h * HIDC + lane] + v1 * ks[h * HIDC + 64 + lane];
    }
#pragma unroll
    for (int off = 32; off; off >>= 1) {
#pragma unroll
        for (int h = 0; h < NHEADS; h++) {
            sv[h] += __shfl_xor(sv[h], off);
            tv[h] += __shfl_xor(tv[h], off);
        }
    }
    if (lane == 0) {
#pragma unroll
        for (int h = 0; h < NHEADS; h++) { s[row * 4 + h] = sv[h]; t[row * 4 + h] = tv[h]; }
    }
}

// ---------------- alpha + leaky_relu + segment_max(atomicMax) ----------------
__global__ void k_alpha(const int* __restrict__ ei, const int* __restrict__ et,
                        const float* __restrict__ s, const float* __restrict__ t,
                        float* __restrict__ alpha, unsigned* __restrict__ amaxK) {
    int e = blockIdx.x * 256 + threadIdx.x;
    if (e >= EE) return;
    int src = ei[e], dst = ei[EE + e], r = et[e];
    float4 si = *(const float4*)&s[(size_t)(dst * RR + r) * 4];
    float4 tj = *(const float4*)&t[(size_t)(src * RR + r) * 4];
    float a0 = si.x + tj.x, a1 = si.y + tj.y, a2 = si.z + tj.z, a3 = si.w + tj.w;
    a0 = a0 >= 0.f ? a0 : 0.2f * a0;
    a1 = a1 >= 0.f ? a1 : 0.2f * a1;
    a2 = a2 >= 0.f ? a2 : 0.2f * a2;
    a3 = a3 >= 0.f ? a3 : 0.2f * a3;
    *(float4*)&alpha[(size_t)e * 4] = float4{a0, a1, a2, a3};
    atomicMax(&amaxK[dst * 4 + 0], fkey(a0));
    atomicMax(&amaxK[dst * 4 + 1], fkey(a1));
    atomicMax(&amaxK[dst * 4 + 2], fkey(a2));
    atomicMax(&amaxK[dst * 4 + 3], fkey(a3));
}

// ---------------- unmap keys -> float, where(!finite)->0 ----------------
__global__ void k_amaxfin(unsigned* __restrict__ amaxK) {
    int i = blockIdx.x * 256 + threadIdx.x;
    if (i >= NN * NHEADS) return;
    unsigned kk = amaxK[i];
    float f = (kk & 0x80000000u) ? __uint_as_float(kk & 0x7FFFFFFFu)
                                 : __uint_as_float(~kk);
    if (!isfinite(f)) f = 0.f;
    ((float*)amaxK)[i] = f;
}

// ---------------- ex = exp(alpha - amax[dst]); den = segment_sum ----------------
__global__ void k_ex(const int* __restrict__ ei, float* __restrict__ alpha,
                     const float* __restrict__ amaxF, float* __restrict__ den) {
    int e = blockIdx.x * 256 + threadIdx.x;
    if (e >= EE) return;
    int dst = ei[EE + e];
    float4 a = *(const float4*)&alpha[(size_t)e * 4];
    float4 m = *(const float4*)&amaxF[(size_t)dst * 4];
    float e0 = expf(a.x - m.x), e1 = expf(a.y - m.y);
    float e2 = expf(a.z - m.z), e3 = expf(a.w - m.w);
    *(float4*)&alpha[(size_t)e * 4] = float4{e0, e1, e2, e3};
    atomicAdd(&den[dst * 4 + 0], e0);
    atomicAdd(&den[dst * 4 + 1], e1);
    atomicAdd(&den[dst * 4 + 2], e2);
    atomicAdd(&den[dst * 4 + 3], e3);
}

// ---------------- aggregation: acc[dst,:] += attn * xw[src,et,:] ----------------
__global__ __launch_bounds__(256) void k_agg(const int* __restrict__ ei,
                                             const int* __restrict__ et,
                                             const float* __restrict__ exb,
                                             const float* __restrict__ den,
                                             const bf16* __restrict__ xw,
                                             float* __restrict__ acc) {
    int e = blockIdx.x * 4 + (threadIdx.x >> 6);
    int lane = threadIdx.x & 63;
    if (e >= EE) return;
    int src = ei[e], dst = ei[EE + e], r = et[e];
    int h = lane >> 4;
    float w = exb[(size_t)e * 4 + h] / (den[dst * 4 + h] + 1e-16f);
    ushort2 uv = *(const ushort2*)((const u16*)xw + (size_t)(src * RR + r) * HIDC + lane * 2);
    atomicAdd(&acc[(size_t)dst * HIDC + lane * 2], w * us2f(uv.x));
    atomicAdd(&acc[(size_t)dst * HIDC + lane * 2 + 1], w * us2f(uv.y));
}

// ---------------- bias + relu + LN (+ residual) ----------------
__global__ __launch_bounds__(256) void k_post(const float* __restrict__ acc,
                                              const void* __restrict__ b,
                                              const void* __restrict__ g,
                                              const void* __restrict__ bb,
                                              const float* __restrict__ hprev,
                                              float* __restrict__ hout,
                                              const int* __restrict__ fl) {
    int n = blockIdx.x * 4 + (threadIdx.x >> 6);
    int lane = threadIdx.x & 63;
    if (n >= NN) return;
    const bool f = fl[0] != 0;
    float v0 = acc[(size_t)n * HIDC + lane] + ldf(b, lane, f);
    float v1 = acc[(size_t)n * HIDC + 64 + lane] + ldf(b, 64 + lane, f);
    v0 = fmaxf(v0, 0.f);
    v1 = fmaxf(v1, 0.f);
    float sum = v0 + v1;
#pragma unroll
    for (int off = 32; off; off >>= 1) sum += __shfl_xor(sum, off);
    float mean = sum * (1.f / 128.f);
    float d0 = v0 - mean, d1 = v1 - mean;
    float sq = d0 * d0 + d1 * d1;
#pragma unroll
    for (int off = 32; off; off >>= 1) sq += __shfl_xor(sq, off);
    float rstd = rsqrtf(sq * (1.f / 128.f) + 1e-5f);
    float y0 = d0 * rstd * ldf(g, lane, f) + ldf(bb, lane, f);
    float y1 = d1 * rstd * ldf(g, lane + 64, f) + ldf(bb, lane + 64, f);
    if (hprev) { y0 += hprev[(size_t)n * HIDC + lane]; y1 += hprev[(size_t)n * HIDC + 64 + lane]; }
    hout[(size_t)n * HIDC + lane] = y0;
    hout[(size_t)n * HIDC + 64 + lane] = y1;
}

// ---------------- decode: gelu(concat(h[a],h[b]) @ mw1 + mb1) @ mw2 + mb2 ----------------
__global__ __launch_bounds__(256) void k_decode(const float* __restrict__ h,
                                                const int* __restrict__ edges,
                                                const void* __restrict__ mw1,
                                                const void* __restrict__ mb1,
                                                const void* __restrict__ mw2,
                                                const void* __restrict__ mb2,
                                                void* __restrict__ out,
                                                const int* __restrict__ fl) {
    __shared__ u16 WsU[HIDC * HIDC];  // 32 KB
    __shared__ float zs[32][132];     // ~16.9 KB, padded
    __shared__ float w2s[HIDC * NCL]; // 4 KB
    __shared__ float mb2s[NCL];
    const int tid = threadIdx.x;
    const int p0 = blockIdx.x * 32;
    const bool f = fl[0] != 0;
    for (int v = tid; v < HIDC * NCL; v += 256) w2s[v] = ldf(mw2, v, f);
    if (tid < NCL) mb2s[tid] = ldf(mb2, tid, f);
    const int pp = tid >> 3;        // pair 0..31
    const int jb = (tid & 7) * 16;  // 16 contiguous output cols per thread
    float accv[16] = {};
    for (int half = 0; half < 2; ++half) {
        __syncthreads();
        if (f) {
            const float* W1h = (const float*)mw1 + half * HIDC * HIDC;
            for (int v = tid; v < HIDC * HIDC / 4; v += 256) {
                float4 w4 = ((const float4*)W1h)[v];
                ushort4 o = {f2us(w4.x), f2us(w4.y), f2us(w4.z), f2us(w4.w)};
                ((ushort4*)WsU)[v] = o;
            }
        } else {
            const u16* W1h = (const u16*)mw1 + half * HIDC * HIDC;
            for (int v = tid; v < HIDC * HIDC / 4; v += 256)
                ((ushort4*)WsU)[v] = ((const ushort4*)W1h)[v];
        }
        for (int v = tid; v < 1024; v += 256) {
            int p = v >> 5, c = (v & 31) * 4;
            int node = edges[(size_t)(p0 + p) * 2 + half];
            *(float4*)&zs[p][c] = *(const float4*)&h[(size_t)node * HIDC + c];
        }
        __syncthreads();
        for (int i = 0; i < HIDC; i++) {
            float zv = zs[pp][i];
            const u16* wr = &WsU[i * HIDC + jb];
#pragma unroll
            for (int u4 = 0; u4 < 4; u4++) {
                ushort4 wu = *(const ushort4*)(wr + u4 * 4);
                accv[u4 * 4 + 0] += zv * us2f(wu.x);
                accv[u4 * 4 + 1] += zv * us2f(wu.y);
                accv[u4 * 4 + 2] += zv * us2f(wu.z);
                accv[u4 * 4 + 3] += zv * us2f(wu.w);
            }
        }
    }
    __syncthreads();
#pragma unroll
    for (int jj = 0; jj < 16; jj++) {
        int j = jb + jj;
        float z = accv[jj] + ldf(mb1, j, f);
        zs[pp][j] = 0.5f * z * (1.f + erff(z * 0.70710678118654752f));
    }
    __syncthreads();
    int p = tid >> 3, c = tid & 7;
    float o = mb2s[c];
    for (int j = 0; j < HIDC; j++) o += zs[p][j] * w2s[j * NCL + c];
    size_t oi = (size_t)(p0 + p) * NCL + c;
    if (f) ((float*)out)[oi] = o;
    else   ((bf16*)out)[oi] = __float2bfloat16(o);
}

extern "C" void kernel_launch(void* const* d_in, const int* in_sizes, int n_in,
                              void* d_out, int out_size, void* d_ws, size_t ws_size,
                              hipStream_t stream) {
    (void)in_sizes; (void)n_in; (void)out_size; (void)ws_size;
    const void* x    = d_in[0];
    const int* ei    = (const int*)d_in[1];
    const int* et    = (const int*)d_in[2];
    const int* edges = (const int*)d_in[3];
    const void* w1 = d_in[4];
    const void* q1 = d_in[5];
    const void* k1 = d_in[6];
    const void* b1 = d_in[7];
    const void* w2 = d_in[8];
    const void* q2 = d_in[9];
    const void* k2 = d_in[10];
    const void* b2 = d_in[11];
    const void* ln1g = d_in[12];
    const void* ln1b = d_in[13];
    const void* ln2g = d_in[14];
    const void* ln2b = d_in[15];
    const void* mw1 = d_in[16];
    const void* mb1 = d_in[17];
    const void* mw2 = d_in[18];
    const void* mb2 = d_in[19];

    // workspace layout, total ~178.24 MB + flags
    char* ws = (char*)d_ws;
    bf16* xwb   = (bf16*)ws;                               // 51.2M bf16
    float* sbuf = (float*)(ws + 102400000);                // 1.6M f32
    float* tbuf = sbuf + NN * RR * NHEADS;                 // 1.6M f32
    float* alp  = tbuf + NN * RR * NHEADS;                 // 2.56M f32
    float* amax = alp + (size_t)EE * NHEADS;               // 200K f32
    float* den  = amax + NN * NHEADS;                      // 200K f32
    float* acc  = den + NN * NHEADS;                       // 6.4M f32 (aliased as hsum)
    float* h1   = acc + (size_t)NN * HIDC;                 // 6.4M f32
    float* hsum = acc;                                     // alias (safe: per-thread read-before-write)
    int* flags  = (int*)(h1 + (size_t)NN * HIDC);          // [0]=input f32?, [1]=1 const

    k_sniff<<<1, 256, 0, stream>>>((const u16*)x, flags);

    for (int layer = 0; layer < 2; ++layer) {
        const void* W  = layer ? w2 : w1;
        const void* q  = layer ? q2 : q1;
        const void* k  = layer ? k2 : k1;
        const void* b  = layer ? b2 : b1;
        const void* lg = layer ? ln2g : ln1g;
        const void* lb = layer ? ln2b : ln1b;
        k_init<<<25000, 256, 0, stream>>>((unsigned*)amax, den, acc);
        k_xw<<<dim3(1563, 8), 256, 0, stream>>>(layer ? (const void*)h1 : x, W, xwb,
                                                layer ? flags + 1 : flags, flags);
        k_st<<<100000, 256, 0, stream>>>(xwb, q, k, sbuf, tbuf, flags);
        k_alpha<<<2500, 256, 0, stream>>>(ei, et, sbuf, tbuf, alp, (unsigned*)amax);
        k_amaxfin<<<782, 256, 0, stream>>>((unsigned*)amax);
        k_ex<<<2500, 256, 0, stream>>>(ei, alp, amax, den);
        k_agg<<<160000, 256, 0, stream>>>(ei, et, alp, den, xwb, acc);
        k_post<<<12500, 256, 0, stream>>>(acc, b, lg, lb,
                                          layer ? h1 : (const float*)nullptr,
                                          layer ? hsum : h1, flags);
    }
    k_decode<<<6250, 256, 0, stream>>>(hsum, edges, mw1, mb1, mw2, mb2, d_out, flags);
}

// Round 4
// 1675.890 us; speedup vs baseline: 2.0241x; 2.0241x over previous
//
#include <hip/hip_runtime.h>
#include <hip/hip_bf16.h>

#define NN    50000
#define RR    8
#define HIDC  128
#define NHEADS 4
#define EE    640000
#define EE2   200000
#define NCL   8

typedef __hip_bfloat16 bf16;
typedef unsigned short u16;
typedef __attribute__((ext_vector_type(8))) short short8;
typedef __attribute__((ext_vector_type(4))) float floatx4;

__device__ __forceinline__ float us2f(u16 u) {
    return __uint_as_float(((unsigned)u) << 16);
}
__device__ __forceinline__ float bf2f(bf16 v) { return __bfloat162float(v); }
__device__ __forceinline__ u16 f2us(float f) {
    bf16 h = __float2bfloat16(f);
    return *(u16*)&h;
}
__device__ __forceinline__ float ldf(const void* p, int i, bool f32) {
    return f32 ? ((const float*)p)[i] : us2f(((const u16*)p)[i]);
}
__device__ __forceinline__ float wredmax(float v) {
#pragma unroll
    for (int off = 32; off; off >>= 1) v = fmaxf(v, __shfl_xor(v, off));
    return v;
}
__device__ __forceinline__ float wredsum(float v) {
#pragma unroll
    for (int off = 32; off; off >>= 1) v += __shfl_xor(v, off);
    return v;
}

// ---------------- dtype sniff: fp32 data viewed as bf16 has exp==0xFF hits ----------------
__global__ void k_sniff(const u16* __restrict__ x, int* __restrict__ flags) {
    __shared__ int cnt;
    if (threadIdx.x == 0) cnt = 0;
    __syncthreads();
    int c = 0;
    for (int i = threadIdx.x; i < 262144; i += 256)
        if (((x[i] >> 7) & 0xFF) == 0xFF) c++;
    atomicAdd(&cnt, c);
    __syncthreads();
    if (threadIdx.x == 0) { flags[0] = (cnt > 32) ? 1 : 0; flags[1] = 1; }
}

// ---------------- CSR build ----------------
__global__ void k_zero(int* __restrict__ p, int n) {
    int i = blockIdx.x * 256 + threadIdx.x;
    if (i < n) p[i] = 0;
}
__global__ void k_hist(const int* __restrict__ ei, int* __restrict__ deg) {
    int e = blockIdx.x * 256 + threadIdx.x;
    if (e < EE) atomicAdd(&deg[ei[EE + e]], 1);
}
// 1 block, 1024 threads: exclusive scan of deg[NN] -> rowptr[NN+1]; cursor=rowptr copy
__global__ __launch_bounds__(1024) void k_scan(int* __restrict__ deg /*in: deg, out: cursor*/,
                                               int* __restrict__ rowptr) {
    __shared__ int part[1024];
    const int t = threadIdx.x;
    const int CH = 49;  // 1024*49 >= 50000
    int lo = t * CH, hi = lo + CH;
    if (hi > NN) hi = NN;
    int base = 0;
    for (int i = lo; i < hi; i++) base += deg[i];
    part[t] = base;
    __syncthreads();
    for (int off = 1; off < 1024; off <<= 1) {
        int v = (t >= off) ? part[t - off] : 0;
        __syncthreads();
        part[t] += v;
        __syncthreads();
    }
    int excl = (t == 0) ? 0 : part[t - 1];
    for (int i = lo; i < hi; i++) {
        int dv = deg[i];
        rowptr[i] = excl;
        deg[i] = excl;  // cursor copy (in-place: read dv first)
        excl += dv;
    }
    if (t == 1023) rowptr[NN] = part[1023];
}
__global__ void k_scatter(const int* __restrict__ ei, int* __restrict__ cursor,
                          int* __restrict__ elist) {
    int e = blockIdx.x * 256 + threadIdx.x;
    if (e >= EE) return;
    int pos = atomicAdd(&cursor[ei[EE + e]], 1);
    elist[pos] = e;
}

// ---------------- xw[n,r,:] = X[n,:] @ W[r]  (bf16 out) ----------------
__global__ __launch_bounds__(256) void k_xw(const void* __restrict__ X,
                                            const void* __restrict__ W,
                                            bf16* __restrict__ xw,
                                            const int* __restrict__ fx,
                                            const int* __restrict__ fw) {
    __shared__ u16 WsU[HIDC * HIDC];   // 32 KB
    __shared__ float Xs[32][HIDC];     // 16 KB
    const int tid = threadIdx.x;
    const int r = blockIdx.y;
    const int n0 = blockIdx.x * 32;
    const bool xf = fx[0] != 0, wf = fw[0] != 0;
    if (wf) {
        const float* Wr = (const float*)W + r * HIDC * HIDC;
        for (int v = tid; v < HIDC * HIDC / 4; v += 256) {
            float4 w4 = ((const float4*)Wr)[v];
            ushort4 o = {f2us(w4.x), f2us(w4.y), f2us(w4.z), f2us(w4.w)};
            ((ushort4*)WsU)[v] = o;
        }
    } else {
        const u16* Wr = (const u16*)W + r * HIDC * HIDC;
        for (int v = tid; v < HIDC * HIDC / 4; v += 256)
            ((ushort4*)WsU)[v] = ((const ushort4*)Wr)[v];
    }
    for (int v = tid; v < 32 * HIDC / 4; v += 256) {
        int row = v >> 5, c = (v & 31) * 4, n = n0 + row;
        float4 val = {0.f, 0.f, 0.f, 0.f};
        if (n < NN) {
            if (xf) val = *(const float4*)((const float*)X + (size_t)n * HIDC + c);
            else {
                ushort4 u = *(const ushort4*)((const u16*)X + (size_t)n * HIDC + c);
                val = float4{us2f(u.x), us2f(u.y), us2f(u.z), us2f(u.w)};
            }
        }
        *(float4*)&Xs[row][c] = val;
    }
    __syncthreads();
    const int to = (tid & 31) * 4;
    const int tn = (tid >> 5) * 4;
    float acc[4][4] = {};
    for (int i = 0; i < HIDC; i += 4) {
        float4 xv[4], wv[4];
#pragma unroll
        for (int a = 0; a < 4; a++) xv[a] = *(const float4*)&Xs[tn + a][i];
#pragma unroll
        for (int b = 0; b < 4; b++) {
            ushort4 wu = *(const ushort4*)&WsU[(i + b) * HIDC + to];
            wv[b] = float4{us2f(wu.x), us2f(wu.y), us2f(wu.z), us2f(wu.w)};
        }
#pragma unroll
        for (int a = 0; a < 4; a++) {
            float4 xa = xv[a];
            acc[a][0] += xa.x * wv[0].x + xa.y * wv[1].x + xa.z * wv[2].x + xa.w * wv[3].x;
            acc[a][1] += xa.x * wv[0].y + xa.y * wv[1].y + xa.z * wv[2].y + xa.w * wv[3].y;
            acc[a][2] += xa.x * wv[0].z + xa.y * wv[1].z + xa.z * wv[2].z + xa.w * wv[3].z;
            acc[a][3] += xa.x * wv[0].w + xa.y * wv[1].w + xa.z * wv[2].w + xa.w * wv[3].w;
        }
    }
#pragma unroll
    for (int a = 0; a < 4; a++) {
        int n = n0 + tn + a;
        if (n < NN) {
            ushort4 o = {f2us(acc[a][0]), f2us(acc[a][1]), f2us(acc[a][2]), f2us(acc[a][3])};
            *(ushort4*)((u16*)xw + (size_t)(n * RR + r) * HIDC + to) = o;
        }
    }
}

// ---------------- s[n,r,h]=xw[n,r,:]@q[:,h]; t likewise with k ----------------
__global__ __launch_bounds__(256) void k_st(const bf16* __restrict__ xw,
                                            const void* __restrict__ q,
                                            const void* __restrict__ k,
                                            float* __restrict__ s, float* __restrict__ t,
                                            const int* __restrict__ fl) {
    __shared__ float qs[NHEADS * HIDC];
    __shared__ float ks[NHEADS * HIDC];
    const bool f = fl[0] != 0;
    for (int v = threadIdx.x; v < HIDC * NHEADS; v += 256) {
        int hh = v & 3; int i = v >> 2;
        qs[hh * HIDC + i] = ldf(q, v, f);
        ks[hh * HIDC + i] = ldf(k, v, f);
    }
    __syncthreads();
    int lane = threadIdx.x & 63;
    int row = blockIdx.x * 4 + (threadIdx.x >> 6);
    if (row >= NN * RR) return;
    const bf16* xr = xw + (size_t)row * HIDC;
    float v0 = bf2f(xr[lane]), v1 = bf2f(xr[lane + 64]);
    float sv[NHEADS], tv[NHEADS];
#pragma unroll
    for (int h = 0; h < NHEADS; h++) {
        sv[h] = v0 * qs[h * HIDC + lane] + v1 * qs[h * HIDC + 64 + lane];
        tv[h] = v0 * ks[h * HIDC + lane] + v1 * ks[h * HIDC + 64 + lane];
    }
#pragma unroll
    for (int off = 32; off; off >>= 1) {
#pragma unroll
        for (int h = 0; h < NHEADS; h++) {
            sv[h] += __shfl_xor(sv[h], off);
            tv[h] += __shfl_xor(tv[h], off);
        }
    }
    if (lane == 0) {
#pragma unroll
        for (int h = 0; h < NHEADS; h++) { s[row * 4 + h] = sv[h]; t[row * 4 + h] = tv[h]; }
    }
}

// ---------------- fused attention: softmax over CSR edges + aggregate + bias/ReLU/LN ----------------
// wave per dst node; online softmax, register accumulation, no atomics
__global__ __launch_bounds__(256) void k_attn(const int* __restrict__ rowptr,
                                              const int* __restrict__ elist,
                                              const int* __restrict__ ei,
                                              const int* __restrict__ et,
                                              const float* __restrict__ sb,
                                              const float* __restrict__ tb,
                                              const bf16* __restrict__ xw,
                                              const void* __restrict__ b,
                                              const void* __restrict__ g,
                                              const void* __restrict__ bb,
                                              const float* __restrict__ hprev,
                                              float* __restrict__ hout,
                                              const int* __restrict__ fl) {
    const int lane = threadIdx.x & 63;
    const int d = blockIdx.x * 4 + (threadIdx.x >> 6);
    if (d >= NN) return;
    const bool f = fl[0] != 0;
    const int hl = lane >> 4;  // my head (channels 2*lane, 2*lane+1 -> head lane/16)
    const int start = rowptr[d], end = rowptr[d + 1];
    float m0 = -1e30f, m1 = -1e30f, m2 = -1e30f, m3 = -1e30f;
    float l0 = 0.f, l1 = 0.f, l2 = 0.f, l3 = 0.f;
    float acc0 = 0.f, acc1 = 0.f;
    for (int c0 = start; c0 < end; c0 += 64) {
        int n = end - c0;
        if (n > 64) n = 64;
        float a0, a1, a2, a3;
        int sr = 0;
        if (lane < n) {
            int e = elist[c0 + lane];
            int src = ei[e], r = et[e];
            sr = src * RR + r;
            float4 si = *(const float4*)&sb[(size_t)(d * RR + r) * 4];
            float4 tj = *(const float4*)&tb[(size_t)sr * 4];
            a0 = si.x + tj.x; a0 = a0 >= 0.f ? a0 : 0.2f * a0;
            a1 = si.y + tj.y; a1 = a1 >= 0.f ? a1 : 0.2f * a1;
            a2 = si.z + tj.z; a2 = a2 >= 0.f ? a2 : 0.2f * a2;
            a3 = si.w + tj.w; a3 = a3 >= 0.f ? a3 : 0.2f * a3;
        } else { a0 = a1 = a2 = a3 = -1e30f; }
        float n0 = fmaxf(m0, wredmax(a0));
        float n1 = fmaxf(m1, wredmax(a1));
        float n2 = fmaxf(m2, wredmax(a2));
        float n3 = fmaxf(m3, wredmax(a3));
        float s0 = __expf(m0 - n0), s1 = __expf(m1 - n1);
        float s2 = __expf(m2 - n2), s3 = __expf(m3 - n3);
        float e0 = __expf(a0 - n0), e1 = __expf(a1 - n1);
        float e2 = __expf(a2 - n2), e3 = __expf(a3 - n3);
        l0 = l0 * s0 + wredsum(e0);
        l1 = l1 * s1 + wredsum(e1);
        l2 = l2 * s2 + wredsum(e2);
        l3 = l3 * s3 + wredsum(e3);
        float scl = hl == 0 ? s0 : hl == 1 ? s1 : hl == 2 ? s2 : s3;
        acc0 *= scl; acc1 *= scl;
        for (int j = 0; j < n; j++) {
            int srj = __shfl(sr, j);
            float wx = __shfl(e0, j), wy = __shfl(e1, j);
            float wz = __shfl(e2, j), ww = __shfl(e3, j);
            float wgt = hl == 0 ? wx : hl == 1 ? wy : hl == 2 ? wz : ww;
            ushort2 uv = *(const ushort2*)((const u16*)xw + (size_t)srj * HIDC + lane * 2);
            acc0 += wgt * us2f(uv.x);
            acc1 += wgt * us2f(uv.y);
        }
        m0 = n0; m1 = n1; m2 = n2; m3 = n3;
    }
    float ld = hl == 0 ? l0 : hl == 1 ? l1 : hl == 2 ? l2 : l3;
    float inv = 1.f / (ld + 1e-16f);
    float v0 = acc0 * inv + ldf(b, 2 * lane, f);
    float v1 = acc1 * inv + ldf(b, 2 * lane + 1, f);
    v0 = fmaxf(v0, 0.f);
    v1 = fmaxf(v1, 0.f);
    float mean = wredsum(v0 + v1) * (1.f / 128.f);
    float d0 = v0 - mean, d1 = v1 - mean;
    float rstd = rsqrtf(wredsum(d0 * d0 + d1 * d1) * (1.f / 128.f) + 1e-5f);
    float y0 = d0 * rstd * ldf(g, 2 * lane, f) + ldf(bb, 2 * lane, f);
    float y1 = d1 * rstd * ldf(g, 2 * lane + 1, f) + ldf(bb, 2 * lane + 1, f);
    if (hprev) {
        y0 += hprev[(size_t)d * HIDC + 2 * lane];
        y1 += hprev[(size_t)d * HIDC + 2 * lane + 1];
    }
    *(float2*)&hout[(size_t)d * HIDC + 2 * lane] = float2{y0, y1};
}

// ---------------- mw1 -> B-fragment order (bf16) for MFMA decode ----------------
// Wf index = ((c*8+q)*64+lane)*8+j ; k=q*32+(lane>>4)*8+j ; n=c*16+(lane&15)
__global__ void k_dswz(const void* __restrict__ mw1, u16* __restrict__ Wf,
                       const int* __restrict__ fl) {
    int idx = blockIdx.x * 256 + threadIdx.x;  // 0..4095
    if (idx >= 4096) return;
    const bool f = fl[0] != 0;
    int c = idx >> 9, q = (idx >> 6) & 7, ln = idx & 63;
    int k0 = q * 32 + (ln >> 4) * 8;
    int nn = c * 16 + (ln & 15);
    u16 o[8];
#pragma unroll
    for (int j = 0; j < 8; j++) {
        float v = ldf(mw1, (k0 + j) * HIDC + nn, f);
        o[j] = f2us(v);
    }
    *(ushort4*)&Wf[idx * 8]     = ushort4{o[0], o[1], o[2], o[3]};
    *(ushort4*)&Wf[idx * 8 + 4] = ushort4{o[4], o[5], o[6], o[7]};
}

// ---------------- decode (MFMA): gelu(concat(h[a],h[b]) @ mw1 + mb1) @ mw2 + mb2 ----------------
// 64 pairs/block, 4 waves; wave w computes rows 16w..16w+15, K=256, 8 col-tiles
__global__ __launch_bounds__(256) void k_decode2(const float* __restrict__ h,
                                                 const int* __restrict__ edges,
                                                 const u16* __restrict__ Wf,
                                                 const void* __restrict__ mb1,
                                                 const void* __restrict__ mw2,
                                                 const void* __restrict__ mb2,
                                                 void* __restrict__ out,
                                                 const int* __restrict__ fl) {
    __shared__ u16 AshU[64 * 264];     // 33,792 B ; reused as zs fp32 [64][132]
    __shared__ float w2s[HIDC * NCL];  // 4 KB
    __shared__ float mb2s[NCL];
    const int tid = threadIdx.x;
    const bool f = fl[0] != 0;
    const int p0 = blockIdx.x * 64;
    for (int v = tid; v < HIDC * NCL; v += 256) w2s[v] = ldf(mw2, v, f);
    if (tid < NCL) mb2s[tid] = ldf(mb2, tid, f);
    // stage A tile: 64 pairs x 256 cols (concat h[a],h[b]) as bf16, row stride 264
    for (int v = tid; v < 4096; v += 256) {
        int p = v >> 6, ch = v & 63;
        int half = ch >> 5, cc = (ch & 31) * 4;
        int node = edges[(size_t)(p0 + p) * 2 + half];
        float4 hv = *(const float4*)&h[(size_t)node * HIDC + cc];
        ushort4 o = {f2us(hv.x), f2us(hv.y), f2us(hv.z), f2us(hv.w)};
        *(ushort4*)&AshU[p * 264 + half * HIDC + cc] = o;
    }
    __syncthreads();
    const int w = tid >> 6, lane = tid & 63;
    short8 af[8];
#pragma unroll
    for (int q = 0; q < 8; q++)
        af[q] = *(const short8*)&AshU[(16 * w + (lane & 15)) * 264 + q * 32 + (lane >> 4) * 8];
    __syncthreads();  // A LDS dead -> reuse as zs
    float* zsf = (float*)AshU;  // [64][132]
#pragma unroll
    for (int c = 0; c < 8; c++) {
        floatx4 acc = {0.f, 0.f, 0.f, 0.f};
#pragma unroll
        for (int q = 0; q < 8; q++) {
            short8 bfr = *(const short8*)&Wf[(size_t)(((c * 8 + q) * 64 + lane) * 8)];
            acc = __builtin_amdgcn_mfma_f32_16x16x32_bf16(af[q], bfr, acc, 0, 0, 0);
        }
        int col = c * 16 + (lane & 15);
        float bv = ldf(mb1, col, f);
#pragma unroll
        for (int reg = 0; reg < 4; reg++) {
            int p = 16 * w + (lane >> 4) * 4 + reg;
            float z = acc[reg] + bv;
            zsf[p * 132 + col] = 0.5f * z * (1.f + erff(z * 0.70710678118654752f));
        }
    }
    __syncthreads();
    for (int o = tid; o < 512; o += 256) {
        int p = o >> 3, cc = o & 7;
        float s = mb2s[cc];
        for (int j = 0; j < HIDC; j++) s += zsf[p * 132 + j] * w2s[j * NCL + cc];
        size_t oi = (size_t)(p0 + p) * NCL + cc;
        if (f) ((float*)out)[oi] = s;
        else   ((bf16*)out)[oi] = __float2bfloat16(s);
    }
}

extern "C" void kernel_launch(void* const* d_in, const int* in_sizes, int n_in,
                              void* d_out, int out_size, void* d_ws, size_t ws_size,
                              hipStream_t stream) {
    (void)in_sizes; (void)n_in; (void)out_size; (void)ws_size;
    const void* x    = d_in[0];
    const int* ei    = (const int*)d_in[1];
    const int* et    = (const int*)d_in[2];
    const int* edges = (const int*)d_in[3];
    const void* w1 = d_in[4];
    const void* q1 = d_in[5];
    const void* k1 = d_in[6];
    const void* b1 = d_in[7];
    const void* w2 = d_in[8];
    const void* q2 = d_in[9];
    const void* k2 = d_in[10];
    const void* b2 = d_in[11];
    const void* ln1g = d_in[12];
    const void* ln1b = d_in[13];
    const void* ln2g = d_in[14];
    const void* ln2b = d_in[15];
    const void* mw1 = d_in[16];
    const void* mb1 = d_in[17];
    const void* mw2 = d_in[18];
    const void* mb2 = d_in[19];

    // workspace layout (bytes)
    char* ws = (char*)d_ws;
    bf16* xwb    = (bf16*)ws;                         // 102,400,000 B
    float* sbuf  = (float*)(ws + 102400000);          // 6.4 MB
    float* tbuf  = (float*)(ws + 108800000);          // 6.4 MB
    float* h1    = (float*)(ws + 115200000);          // 25.6 MB
    float* hsum  = (float*)(ws + 140800000);          // 25.6 MB
    int* rowptr  = (int*)(ws + 166400000);            // (NN+1) ints
    int* cursor  = (int*)(ws + 166600016);            // NN ints (deg, then cursor)
    int* elist   = (int*)(ws + 166800016);            // EE ints
    u16* Wf      = (u16*)(ws + 169360016);            // 65,536 B
    int* flags   = (int*)(ws + 169425552);            // 2 ints

    k_sniff<<<1, 256, 0, stream>>>((const u16*)x, flags);

    // CSR build (graph static per call)
    k_zero<<<196, 256, 0, stream>>>(cursor, NN);
    k_hist<<<2500, 256, 0, stream>>>(ei, cursor);
    k_scan<<<1, 1024, 0, stream>>>(cursor, rowptr);
    k_scatter<<<2500, 256, 0, stream>>>(ei, cursor, elist);
    k_dswz<<<16, 256, 0, stream>>>(mw1, Wf, flags);

    for (int layer = 0; layer < 2; ++layer) {
        const void* W  = layer ? w2 : w1;
        const void* q  = layer ? q2 : q1;
        const void* k  = layer ? k2 : k1;
        const void* b  = layer ? b2 : b1;
        const void* lg = layer ? ln2g : ln1g;
        const void* lb = layer ? ln2b : ln1b;
        k_xw<<<dim3(1563, 8), 256, 0, stream>>>(layer ? (const void*)h1 : x, W, xwb,
                                                layer ? flags + 1 : flags, flags);
        k_st<<<100000, 256, 0, stream>>>(xwb, q, k, sbuf, tbuf, flags);
        k_attn<<<12500, 256, 0, stream>>>(rowptr, elist, ei, et, sbuf, tbuf, xwb,
                                          b, lg, lb,
                                          layer ? h1 : (const float*)nullptr,
                                          layer ? hsum : h1, flags);
    }
    k_decode2<<<3125, 256, 0, stream>>>(hsum, edges, Wf, mb1, mw2, mb2, d_out, flags);
}

// Round 6
// 1361.067 us; speedup vs baseline: 2.4923x; 1.2313x over previous
//
#include <hip/hip_runtime.h>
#include <hip/hip_bf16.h>

#define NN    50000
#define RR    8
#define HIDC  128
#define NHEADS 4
#define EE    640000
#define EE2   200000
#define NCL   8

typedef __hip_bfloat16 bf16;
typedef unsigned short u16;
typedef __attribute__((ext_vector_type(8))) short short8;
typedef __attribute__((ext_vector_type(4))) float floatx4;

__device__ __forceinline__ float us2f(u16 u) {
    return __uint_as_float(((unsigned)u) << 16);
}
__device__ __forceinline__ float bf2f(bf16 v) { return __bfloat162float(v); }
__device__ __forceinline__ u16 f2us(float f) {
    bf16 h = __float2bfloat16(f);
    return *(u16*)&h;
}
__device__ __forceinline__ float ldf(const void* p, int i, bool f32) {
    return f32 ? ((const float*)p)[i] : us2f(((const u16*)p)[i]);
}
__device__ __forceinline__ float wredmax(float v) {
#pragma unroll
    for (int off = 32; off; off >>= 1) v = fmaxf(v, __shfl_xor(v, off));
    return v;
}
__device__ __forceinline__ float wredsum(float v) {
#pragma unroll
    for (int off = 32; off; off >>= 1) v += __shfl_xor(v, off);
    return v;
}

// ---------------- dtype sniff: fp32 data viewed as bf16 has exp==0xFF hits ----------------
__global__ void k_sniff(const u16* __restrict__ x, int* __restrict__ flags) {
    __shared__ int cnt;
    if (threadIdx.x == 0) cnt = 0;
    __syncthreads();
    int c = 0;
    for (int i = threadIdx.x; i < 262144; i += 256)
        if (((x[i] >> 7) & 0xFF) == 0xFF) c++;
    atomicAdd(&cnt, c);
    __syncthreads();
    if (threadIdx.x == 0) { flags[0] = (cnt > 32) ? 1 : 0; flags[1] = 1; }
}

// ---------------- CSR build ----------------
__global__ void k_zero(int* __restrict__ p, int n) {
    int i = blockIdx.x * 256 + threadIdx.x;
    if (i < n) p[i] = 0;
}
__global__ void k_hist(const int* __restrict__ ei, int* __restrict__ deg) {
    int e = blockIdx.x * 256 + threadIdx.x;
    if (e < EE) atomicAdd(&deg[ei[EE + e]], 1);
}
__global__ __launch_bounds__(1024) void k_scan(int* __restrict__ deg,
                                               int* __restrict__ rowptr) {
    __shared__ int part[1024];
    const int t = threadIdx.x;
    const int CH = 49;
    int lo = t * CH, hi = lo + CH;
    if (hi > NN) hi = NN;
    if (lo > NN) lo = NN;
    int base = 0;
    for (int i = lo; i < hi; i++) base += deg[i];
    part[t] = base;
    __syncthreads();
    for (int off = 1; off < 1024; off <<= 1) {
        int v = (t >= off) ? part[t - off] : 0;
        __syncthreads();
        part[t] += v;
        __syncthreads();
    }
    int excl = (t == 0) ? 0 : part[t - 1];
    for (int i = lo; i < hi; i++) {
        int dv = deg[i];
        rowptr[i] = excl;
        deg[i] = excl;
        excl += dv;
    }
    if (t == 1023) rowptr[NN] = part[1023];
}
__global__ void k_scatter(const int* __restrict__ ei, int* __restrict__ cursor,
                          int* __restrict__ elist) {
    int e = blockIdx.x * 256 + threadIdx.x;
    if (e >= EE) return;
    int pos = atomicAdd(&cursor[ei[EE + e]], 1);
    elist[pos] = e;
}

// ---------------- W (2 layers x 8 rel, 128x128) -> MFMA B-fragment order ----------------
__global__ void k_wswz(const void* __restrict__ w1, const void* __restrict__ w2,
                       u16* __restrict__ Wf2, const int* __restrict__ fl) {
    int idx = blockIdx.x * 256 + threadIdx.x;  // 0..32767
    if (idx >= 32768) return;
    const bool f = fl[0] != 0;
    int mat = idx >> 11, rest = idx & 2047;
    int c = rest >> 8, q = (rest >> 6) & 3, ln = rest & 63;
    int k0 = q * 32 + (ln >> 4) * 8;
    int nn = c * 16 + (ln & 15);
    const void* W = (mat >= 8) ? w2 : w1;
    int r = mat & 7;
    u16 o[8];
#pragma unroll
    for (int j = 0; j < 8; j++)
        o[j] = f2us(ldf(W, (r * HIDC + k0 + j) * HIDC + nn, f));
    u16* dst = Wf2 + (size_t)mat * 16384 + (size_t)(((c * 4 + q) * 64 + ln) * 8);
    *(ushort4*)dst       = ushort4{o[0], o[1], o[2], o[3]};
    *(ushort4*)(dst + 4) = ushort4{o[4], o[5], o[6], o[7]};
}

// ---------------- MFMA xw (fp32 LDS epilogue, decode2-identical) ----------------
// grid (ceil(N/64), 8), block 256 (4 waves). Wave w: nodes 16w..16w+15.
__global__ __launch_bounds__(256) void k_xw2(const void* __restrict__ X,
                                             const u16* __restrict__ Wf2,
                                             bf16* __restrict__ xw,
                                             const int* __restrict__ fx,
                                             int layer) {
    __shared__ u16 Xs[64 * 136];    // 17.4 KB bf16 input tile
    __shared__ float Os[64 * 132];  // 33.8 KB fp32 output tile
    const int tid = threadIdx.x;
    const int r = blockIdx.y;
    const int n0 = blockIdx.x * 64;
    const bool xf = fx[0] != 0;
    for (int v = tid; v < 2048; v += 256) {
        int row = v >> 5, c4 = (v & 31) * 4, n = n0 + row;
        ushort4 o = {0, 0, 0, 0};
        if (n < NN) {
            if (xf) {
                float4 hv = *(const float4*)((const float*)X + (size_t)n * HIDC + c4);
                o = ushort4{f2us(hv.x), f2us(hv.y), f2us(hv.z), f2us(hv.w)};
            } else {
                o = *(const ushort4*)((const u16*)X + (size_t)n * HIDC + c4);
            }
        }
        *(ushort4*)&Xs[row * 136 + c4] = o;
    }
    __syncthreads();
    const int w = tid >> 6, lane = tid & 63;
    short8 af[4];
#pragma unroll
    for (int q = 0; q < 4; q++)
        af[q] = *(const short8*)&Xs[(16 * w + (lane & 15)) * 136 + q * 32 + (lane >> 4) * 8];
    const u16* Wfr = Wf2 + (size_t)(layer * 8 + r) * 16384;
#pragma unroll
    for (int c = 0; c < 8; c++) {
        floatx4 acc = {0.f, 0.f, 0.f, 0.f};
#pragma unroll
        for (int q = 0; q < 4; q++) {
            short8 bfr = *(const short8*)&Wfr[(size_t)(((c * 4 + q) * 64 + lane) * 8)];
            acc = __builtin_amdgcn_mfma_f32_16x16x32_bf16(af[q], bfr, acc, 0, 0, 0);
        }
        int col = c * 16 + (lane & 15);
#pragma unroll
        for (int reg = 0; reg < 4; reg++) {
            int p = 16 * w + (lane >> 4) * 4 + reg;
            Os[p * 132 + col] = acc[reg];
        }
    }
    __syncthreads();
    for (int v = tid; v < 2048; v += 256) {
        int row = v >> 5, c4 = (v & 31) * 4, n = n0 + row;
        if (n < NN) {
            float4 hv = *(const float4*)&Os[row * 132 + c4];
            ushort4 o = {f2us(hv.x), f2us(hv.y), f2us(hv.z), f2us(hv.w)};
            *(ushort4*)((u16*)xw + (size_t)(n * RR + r) * HIDC + c4) = o;
        }
    }
}

// ---------------- s[n,r,h]=xw[n,r,:]@q[:,h]; t likewise with k ----------------
__global__ __launch_bounds__(256) void k_st(const bf16* __restrict__ xw,
                                            const void* __restrict__ q,
                                            const void* __restrict__ k,
                                            float* __restrict__ s, float* __restrict__ t,
                                            const int* __restrict__ fl) {
    __shared__ float qs[NHEADS * HIDC];
    __shared__ float ks[NHEADS * HIDC];
    const bool f = fl[0] != 0;
    for (int v = threadIdx.x; v < HIDC * NHEADS; v += 256) {
        int hh = v & 3; int i = v >> 2;
        qs[hh * HIDC + i] = ldf(q, v, f);
        ks[hh * HIDC + i] = ldf(k, v, f);
    }
    __syncthreads();
    int lane = threadIdx.x & 63;
    int row = blockIdx.x * 4 + (threadIdx.x >> 6);
    if (row >= NN * RR) return;
    const bf16* xr = xw + (size_t)row * HIDC;
    float v0 = bf2f(xr[lane]), v1 = bf2f(xr[lane + 64]);
    float sv[NHEADS], tv[NHEADS];
#pragma unroll
    for (int h = 0; h < NHEADS; h++) {
        sv[h] = v0 * qs[h * HIDC + lane] + v1 * qs[h * HIDC + 64 + lane];
        tv[h] = v0 * ks[h * HIDC + lane] + v1 * ks[h * HIDC + 64 + lane];
    }
#pragma unroll
    for (int off = 32; off; off >>= 1) {
#pragma unroll
        for (int h = 0; h < NHEADS; h++) {
            sv[h] += __shfl_xor(sv[h], off);
            tv[h] += __shfl_xor(tv[h], off);
        }
    }
    if (lane == 0) {
#pragma unroll
        for (int h = 0; h < NHEADS; h++) { s[row * 4 + h] = sv[h]; t[row * 4 + h] = tv[h]; }
    }
}

// ---------------- fused attention: softmax over CSR edges + aggregate + bias/ReLU/LN ----------------
__global__ __launch_bounds__(256) void k_attn(const int* __restrict__ rowptr,
                                              const int* __restrict__ elist,
                                              const int* __restrict__ ei,
                                              const int* __restrict__ et,
                                              const float* __restrict__ sb,
                                              const float* __restrict__ tb,
                                              const bf16* __restrict__ xw,
                                              const void* __restrict__ b,
                                              const void* __restrict__ g,
                                              const void* __restrict__ bb,
                                              const float* __restrict__ hprev,
                                              float* __restrict__ hout,
                                              const int* __restrict__ fl) {
    const int lane = threadIdx.x & 63;
    const int d = blockIdx.x * 4 + (threadIdx.x >> 6);
    if (d >= NN) return;
    const bool f = fl[0] != 0;
    const int hl = lane >> 4;
    const int start = rowptr[d], end = rowptr[d + 1];
    float m0 = -1e30f, m1 = -1e30f, m2 = -1e30f, m3 = -1e30f;
    float l0 = 0.f, l1 = 0.f, l2 = 0.f, l3 = 0.f;
    float acc0 = 0.f, acc1 = 0.f;
    for (int c0 = start; c0 < end; c0 += 64) {
        int n = end - c0;
        if (n > 64) n = 64;
        float a0, a1, a2, a3;
        int sr = 0;
        if (lane < n) {
            int e = elist[c0 + lane];
            int src = ei[e], r = et[e];
            sr = src * RR + r;
            float4 si = *(const float4*)&sb[(size_t)(d * RR + r) * 4];
            float4 tj = *(const float4*)&tb[(size_t)sr * 4];
            a0 = si.x + tj.x; a0 = a0 >= 0.f ? a0 : 0.2f * a0;
            a1 = si.y + tj.y; a1 = a1 >= 0.f ? a1 : 0.2f * a1;
            a2 = si.z + tj.z; a2 = a2 >= 0.f ? a2 : 0.2f * a2;
            a3 = si.w + tj.w; a3 = a3 >= 0.f ? a3 : 0.2f * a3;
        } else { a0 = a1 = a2 = a3 = -1e30f; }
        float n0 = fmaxf(m0, wredmax(a0));
        float n1 = fmaxf(m1, wredmax(a1));
        float n2 = fmaxf(m2, wredmax(a2));
        float n3 = fmaxf(m3, wredmax(a3));
        float s0 = __expf(m0 - n0), s1 = __expf(m1 - n1);
        float s2 = __expf(m2 - n2), s3 = __expf(m3 - n3);
        float e0 = __expf(a0 - n0), e1 = __expf(a1 - n1);
        float e2 = __expf(a2 - n2), e3 = __expf(a3 - n3);
        l0 = l0 * s0 + wredsum(e0);
        l1 = l1 * s1 + wredsum(e1);
        l2 = l2 * s2 + wredsum(e2);
        l3 = l3 * s3 + wredsum(e3);
        float scl = hl == 0 ? s0 : hl == 1 ? s1 : hl == 2 ? s2 : s3;
        acc0 *= scl; acc1 *= scl;
        for (int j = 0; j < n; j++) {
            int srj = __shfl(sr, j);
            float wx = __shfl(e0, j), wy = __shfl(e1, j);
            float wz = __shfl(e2, j), ww = __shfl(e3, j);
            float wgt = hl == 0 ? wx : hl == 1 ? wy : hl == 2 ? wz : ww;
            ushort2 uv = *(const ushort2*)((const u16*)xw + (size_t)srj * HIDC + lane * 2);
            acc0 += wgt * us2f(uv.x);
            acc1 += wgt * us2f(uv.y);
        }
        m0 = n0; m1 = n1; m2 = n2; m3 = n3;
    }
    float ld = hl == 0 ? l0 : hl == 1 ? l1 : hl == 2 ? l2 : l3;
    float inv = 1.f / (ld + 1e-16f);
    float v0 = acc0 * inv + ldf(b, 2 * lane, f);
    float v1 = acc1 * inv + ldf(b, 2 * lane + 1, f);
    v0 = fmaxf(v0, 0.f);
    v1 = fmaxf(v1, 0.f);
    float mean = wredsum(v0 + v1) * (1.f / 128.f);
    float d0 = v0 - mean, d1 = v1 - mean;
    float rstd = rsqrtf(wredsum(d0 * d0 + d1 * d1) * (1.f / 128.f) + 1e-5f);
    float y0 = d0 * rstd * ldf(g, 2 * lane, f) + ldf(bb, 2 * lane, f);
    float y1 = d1 * rstd * ldf(g, 2 * lane + 1, f) + ldf(bb, 2 * lane + 1, f);
    if (hprev) {
        y0 += hprev[(size_t)d * HIDC + 2 * lane];
        y1 += hprev[(size_t)d * HIDC + 2 * lane + 1];
    }
    *(float2*)&hout[(size_t)d * HIDC + 2 * lane] = float2{y0, y1};
}

// ---------------- mw1 -> B-fragment order (bf16) for MFMA decode ----------------
__global__ void k_dswz(const void* __restrict__ mw1, u16* __restrict__ Wf,
                       const int* __restrict__ fl) {
    int idx = blockIdx.x * 256 + threadIdx.x;  // 0..4095
    if (idx >= 4096) return;
    const bool f = fl[0] != 0;
    int c = idx >> 9, q = (idx >> 6) & 7, ln = idx & 63;
    int k0 = q * 32 + (ln >> 4) * 8;
    int nn = c * 16 + (ln & 15);
    u16 o[8];
#pragma unroll
    for (int j = 0; j < 8; j++) {
        float v = ldf(mw1, (k0 + j) * HIDC + nn, f);
        o[j] = f2us(v);
    }
    *(ushort4*)&Wf[idx * 8]     = ushort4{o[0], o[1], o[2], o[3]};
    *(ushort4*)&Wf[idx * 8 + 4] = ushort4{o[4], o[5], o[6], o[7]};
}

// ---------------- decode (MFMA) ----------------
__global__ __launch_bounds__(256) void k_decode2(const float* __restrict__ h,
                                                 const int* __restrict__ edges,
                                                 const u16* __restrict__ Wf,
                                                 const void* __restrict__ mb1,
                                                 const void* __restrict__ mw2,
                                                 const void* __restrict__ mb2,
                                                 void* __restrict__ out,
                                                 const int* __restrict__ fl) {
    __shared__ u16 AshU[64 * 264];
    __shared__ float w2s[HIDC * NCL];
    __shared__ float mb2s[NCL];
    const int tid = threadIdx.x;
    const bool f = fl[0] != 0;
    const int p0 = blockIdx.x * 64;
    for (int v = tid; v < HIDC * NCL; v += 256) w2s[v] = ldf(mw2, v, f);
    if (tid < NCL) mb2s[tid] = ldf(mb2, tid, f);
    for (int v = tid; v < 4096; v += 256) {
        int p = v >> 6, ch = v & 63;
        int half = ch >> 5, cc = (ch & 31) * 4;
        int node = edges[(size_t)(p0 + p) * 2 + half];
        float4 hv = *(const float4*)&h[(size_t)node * HIDC + cc];
        ushort4 o = {f2us(hv.x), f2us(hv.y), f2us(hv.z), f2us(hv.w)};
        *(ushort4*)&AshU[p * 264 + half * HIDC + cc] = o;
    }
    __syncthreads();
    const int w = tid >> 6, lane = tid & 63;
    short8 af[8];
#pragma unroll
    for (int q = 0; q < 8; q++)
        af[q] = *(const short8*)&AshU[(16 * w + (lane & 15)) * 264 + q * 32 + (lane >> 4) * 8];
    __syncthreads();
    float* zsf = (float*)AshU;  // [64][132]
#pragma unroll
    for (int c = 0; c < 8; c++) {
        floatx4 acc = {0.f, 0.f, 0.f, 0.f};
#pragma unroll
        for (int q = 0; q < 8; q++) {
            short8 bfr = *(const short8*)&Wf[(size_t)(((c * 8 + q) * 64 + lane) * 8)];
            acc = __builtin_amdgcn_mfma_f32_16x16x32_bf16(af[q], bfr, acc, 0, 0, 0);
        }
        int col = c * 16 + (lane & 15);
        float bv = ldf(mb1, col, f);
#pragma unroll
        for (int reg = 0; reg < 4; reg++) {
            int p = 16 * w + (lane >> 4) * 4 + reg;
            float z = acc[reg] + bv;
            zsf[p * 132 + col] = 0.5f * z * (1.f + erff(z * 0.70710678118654752f));
        }
    }
    __syncthreads();
    for (int o = tid; o < 512; o += 256) {
        int p = o >> 3, cc = o & 7;
        float sv = mb2s[cc];
        for (int j = 0; j < HIDC; j++) sv += zsf[p * 132 + j] * w2s[j * NCL + cc];
        size_t oi = (size_t)(p0 + p) * NCL + cc;
        if (f) ((float*)out)[oi] = sv;
        else   ((bf16*)out)[oi] = __float2bfloat16(sv);
    }
}

extern "C" void kernel_launch(void* const* d_in, const int* in_sizes, int n_in,
                              void* d_out, int out_size, void* d_ws, size_t ws_size,
                              hipStream_t stream) {
    (void)in_sizes; (void)n_in; (void)out_size; (void)ws_size;
    const void* x    = d_in[0];
    const int* ei    = (const int*)d_in[1];
    const int* et    = (const int*)d_in[2];
    const int* edges = (const int*)d_in[3];
    const void* w1 = d_in[4];
    const void* q1 = d_in[5];
    const void* k1 = d_in[6];
    const void* b1 = d_in[7];
    const void* w2 = d_in[8];
    const void* q2 = d_in[9];
    const void* k2 = d_in[10];
    const void* b2 = d_in[11];
    const void* ln1g = d_in[12];
    const void* ln1b = d_in[13];
    const void* ln2g = d_in[14];
    const void* ln2b = d_in[15];
    const void* mw1 = d_in[16];
    const void* mb1 = d_in[17];
    const void* mw2 = d_in[18];
    const void* mb2 = d_in[19];

    // workspace layout — stays within the round-4-proven bound (<= 169,425,560 B)
    char* ws = (char*)d_ws;
    bf16* xwb   = (bf16*)ws;                      // [0, 102400000)
    u16* Wf     = (u16*)ws;                       // ALIAS xwb: written (k_dswz) after last xwb read
    float* sbuf = (float*)(ws + 102400000);       // 6.4 MB
    float* tbuf = (float*)(ws + 108800000);       // 6.4 MB
    float* h1   = (float*)(ws + 115200000);       // 25.6 MB
    float* hsum = (float*)(ws + 140800000);       // 25.6 MB
    u16* Wf2    = (u16*)(ws + 140800000);         // ALIAS hsum: dead before hsum is written
    int* rowptr = (int*)(ws + 166400000);         // NN+1 ints
    int* cursor = (int*)(ws + 166600016);         // NN ints
    int* elist  = (int*)(ws + 166800016);         // EE ints
    int* flags  = (int*)(ws + 169360016);         // 2 ints (proven region)

    k_sniff<<<1, 256, 0, stream>>>((const u16*)x, flags);

    // CSR build + layer-weight swizzle (Wf2 lives in hsum space: read only before attn L1)
    k_zero<<<196, 256, 0, stream>>>(cursor, NN);
    k_hist<<<2500, 256, 0, stream>>>(ei, cursor);
    k_scan<<<1, 1024, 0, stream>>>(cursor, rowptr);
    k_scatter<<<2500, 256, 0, stream>>>(ei, cursor, elist);
    k_wswz<<<128, 256, 0, stream>>>(w1, w2, Wf2, flags);

    for (int layer = 0; layer < 2; ++layer) {
        const void* q  = layer ? q2 : q1;
        const void* k  = layer ? k2 : k1;
        const void* b  = layer ? b2 : b1;
        const void* lg = layer ? ln2g : ln1g;
        const void* lb = layer ? ln2b : ln1b;
        k_xw2<<<dim3(782, 8), 256, 0, stream>>>(layer ? (const void*)h1 : x, Wf2, xwb,
                                                layer ? flags + 1 : flags, layer);
        k_st<<<100000, 256, 0, stream>>>(xwb, q, k, sbuf, tbuf, flags);
        k_attn<<<12500, 256, 0, stream>>>(rowptr, elist, ei, et, sbuf, tbuf, xwb,
                                          b, lg, lb,
                                          layer ? h1 : (const float*)nullptr,
                                          layer ? hsum : h1, flags);
    }
    // decode weight swizzle into xwb space (xwb dead after attn L1)
    k_dswz<<<16, 256, 0, stream>>>(mw1, Wf, flags);
    k_decode2<<<3125, 256, 0, stream>>>(hsum, edges, Wf, mb1, mw2, mb2, d_out, flags);
}

// Round 7
// 850.171 us; speedup vs baseline: 3.9901x; 1.6009x over previous
//
#include <hip/hip_runtime.h>
#include <hip/hip_bf16.h>

#define NN    50000
#define RR    8
#define HIDC  128
#define NHEADS 4
#define EE    640000
#define EE2   200000
#define NCL   8

typedef __hip_bfloat16 bf16;
typedef unsigned short u16;
typedef __attribute__((ext_vector_type(8))) short short8;
typedef __attribute__((ext_vector_type(4))) float floatx4;

__device__ __forceinline__ float us2f(u16 u) {
    return __uint_as_float(((unsigned)u) << 16);
}
__device__ __forceinline__ float bf2f(bf16 v) { return __bfloat162float(v); }
__device__ __forceinline__ u16 f2us(float f) {
    bf16 h = __float2bfloat16(f);
    return *(u16*)&h;
}
__device__ __forceinline__ float ldf(const void* p, int i, bool f32) {
    return f32 ? ((const float*)p)[i] : us2f(((const u16*)p)[i]);
}
__device__ __forceinline__ float wredmax(float v) {
#pragma unroll
    for (int off = 32; off; off >>= 1) v = fmaxf(v, __shfl_xor(v, off));
    return v;
}
__device__ __forceinline__ float wredsum(float v) {
#pragma unroll
    for (int off = 32; off; off >>= 1) v += __shfl_xor(v, off);
    return v;
}

// ---------------- dtype sniff: fp32 data viewed as bf16 has exp==0xFF hits ----------------
__global__ void k_sniff(const u16* __restrict__ x, int* __restrict__ flags) {
    __shared__ int cnt;
    if (threadIdx.x == 0) cnt = 0;
    __syncthreads();
    int c = 0;
    for (int i = threadIdx.x; i < 262144; i += 256)
        if (((x[i] >> 7) & 0xFF) == 0xFF) c++;
    atomicAdd(&cnt, c);
    __syncthreads();
    if (threadIdx.x == 0) { flags[0] = (cnt > 32) ? 1 : 0; flags[1] = 1; }
}

// ---------------- CSR build ----------------
__global__ void k_zero(int* __restrict__ p, int n) {
    int i = blockIdx.x * 256 + threadIdx.x;
    if (i < n) p[i] = 0;
}
__global__ void k_hist(const int* __restrict__ ei, int* __restrict__ deg) {
    int e = blockIdx.x * 256 + threadIdx.x;
    if (e < EE) atomicAdd(&deg[ei[EE + e]], 1);
}
__global__ __launch_bounds__(1024) void k_scan(int* __restrict__ deg,
                                               int* __restrict__ rowptr) {
    __shared__ int part[1024];
    const int t = threadIdx.x;
    const int CH = 49;
    int lo = t * CH, hi = lo + CH;
    if (hi > NN) hi = NN;
    if (lo > NN) lo = NN;
    int base = 0;
    for (int i = lo; i < hi; i++) base += deg[i];
    part[t] = base;
    __syncthreads();
    for (int off = 1; off < 1024; off <<= 1) {
        int v = (t >= off) ? part[t - off] : 0;
        __syncthreads();
        part[t] += v;
        __syncthreads();
    }
    int excl = (t == 0) ? 0 : part[t - 1];
    for (int i = lo; i < hi; i++) {
        int dv = deg[i];
        rowptr[i] = excl;
        deg[i] = excl;
        excl += dv;
    }
    if (t == 1023) rowptr[NN] = part[1023];
}
__global__ void k_scatter(const int* __restrict__ ei, int* __restrict__ cursor,
                          int* __restrict__ elist) {
    int e = blockIdx.x * 256 + threadIdx.x;
    if (e >= EE) return;
    int pos = atomicAdd(&cursor[ei[EE + e]], 1);
    elist[pos] = e;
}

// ---------------- qkw[mat][i][h8] = sum_o W[r][i][o] * (q|k)[o][h] ----------------
// mat 0..7 = layer0 rel r, 8..15 = layer1; h8 0..3 -> q heads, 4..7 -> k heads
__global__ void k_qkw(const void* __restrict__ w1, const void* __restrict__ w2,
                      const void* __restrict__ q1, const void* __restrict__ k1,
                      const void* __restrict__ q2, const void* __restrict__ k2,
                      float* __restrict__ qkw, const int* __restrict__ fl) {
    int idx = blockIdx.x * 256 + threadIdx.x;  // 16*128*8 = 16384
    if (idx >= 16384) return;
    const bool f = fl[0] != 0;
    int mat = idx >> 10;
    int i   = (idx >> 3) & 127;
    int h8  = idx & 7;
    const void* W = (mat >= 8) ? w2 : w1;
    const void* qk = (mat >= 8) ? ((h8 < 4) ? q2 : k2) : ((h8 < 4) ? q1 : k1);
    int h = h8 & 3;
    int r = mat & 7;
    float acc = 0.f;
    for (int o = 0; o < HIDC; o++)
        acc += ldf(W, (r * HIDC + i) * HIDC + o, f) * ldf(qk, o * NHEADS + h, f);
    qkw[idx] = acc;
}

// ---------------- W (+qkw cols) -> MFMA B-fragment order: 9 col-tiles ----------------
// per frag (c=colTile 0..8, q=kChunk, lane): k=q*32+(lane>>4)*8+j, n=c*16+(lane&15)
// col-tile 8: cols 128..135 = [Wq h0..3 | Wk h0..3], 136..143 = 0
__global__ void k_wswz(const void* __restrict__ w1, const void* __restrict__ w2,
                       const float* __restrict__ qkw,
                       u16* __restrict__ Wf2, const int* __restrict__ fl) {
    int idx = blockIdx.x * 256 + threadIdx.x;  // 16 * 2304 = 36864
    if (idx >= 36864) return;
    const bool f = fl[0] != 0;
    int mat = idx / 2304, rest = idx % 2304;
    int c = rest >> 8, q = (rest >> 6) & 3, ln = rest & 63;
    int k0 = q * 32 + (ln >> 4) * 8;
    int nn = c * 16 + (ln & 15);
    int r = mat & 7;
    u16 o[8];
    if (c < 8) {
        const void* W = (mat >= 8) ? w2 : w1;
#pragma unroll
        for (int j = 0; j < 8; j++)
            o[j] = f2us(ldf(W, (r * HIDC + k0 + j) * HIDC + nn, f));
    } else {
        int col = nn - 128;  // 0..15
#pragma unroll
        for (int j = 0; j < 8; j++)
            o[j] = (col < 8) ? f2us(qkw[mat * 1024 + (k0 + j) * 8 + col]) : (u16)0;
    }
    u16* dst = Wf2 + (size_t)mat * 18432 + (size_t)(((c * 4 + q) * 64 + ln) * 8);
    *(ushort4*)dst       = ushort4{o[0], o[1], o[2], o[3]};
    *(ushort4*)(dst + 4) = ushort4{o[4], o[5], o[6], o[7]};
}

// ---------------- MFMA xw + s/t from col-tile 8 ----------------
// grid (ceil(N/64), 8), block 256 (4 waves). Wave w: nodes 16w..16w+15.
__global__ __launch_bounds__(256) void k_xw2(const void* __restrict__ X,
                                             const u16* __restrict__ Wf2,
                                             bf16* __restrict__ xw,
                                             float* __restrict__ sbuf,
                                             float* __restrict__ tbuf,
                                             const int* __restrict__ fx,
                                             int layer) {
    __shared__ u16 Xs[64 * 136];    // 17.4 KB bf16 input tile
    __shared__ float Os[64 * 132];  // 33.8 KB fp32 output tile
    const int tid = threadIdx.x;
    const int r = blockIdx.y;
    const int n0 = blockIdx.x * 64;
    const bool xf = fx[0] != 0;
    for (int v = tid; v < 2048; v += 256) {
        int row = v >> 5, c4 = (v & 31) * 4, n = n0 + row;
        ushort4 o = {0, 0, 0, 0};
        if (n < NN) {
            if (xf) {
                float4 hv = *(const float4*)((const float*)X + (size_t)n * HIDC + c4);
                o = ushort4{f2us(hv.x), f2us(hv.y), f2us(hv.z), f2us(hv.w)};
            } else {
                o = *(const ushort4*)((const u16*)X + (size_t)n * HIDC + c4);
            }
        }
        *(ushort4*)&Xs[row * 136 + c4] = o;
    }
    __syncthreads();
    const int w = tid >> 6, lane = tid & 63;
    short8 af[4];
#pragma unroll
    for (int q = 0; q < 4; q++)
        af[q] = *(const short8*)&Xs[(16 * w + (lane & 15)) * 136 + q * 32 + (lane >> 4) * 8];
    const u16* Wfr = Wf2 + (size_t)(layer * 8 + r) * 18432;
#pragma unroll
    for (int c = 0; c < 9; c++) {
        floatx4 acc = {0.f, 0.f, 0.f, 0.f};
#pragma unroll
        for (int q = 0; q < 4; q++) {
            short8 bfr = *(const short8*)&Wfr[(size_t)(((c * 4 + q) * 64 + lane) * 8)];
            acc = __builtin_amdgcn_mfma_f32_16x16x32_bf16(af[q], bfr, acc, 0, 0, 0);
        }
        if (c < 8) {
            int col = c * 16 + (lane & 15);
#pragma unroll
            for (int reg = 0; reg < 4; reg++) {
                int p = 16 * w + (lane >> 4) * 4 + reg;
                Os[p * 132 + col] = acc[reg];
            }
        } else {
            int cl = lane & 15;  // 0..3 -> s heads, 4..7 -> t heads
            if (cl < 8) {
                float* dstp = (cl < 4) ? sbuf : tbuf;
                int h = cl & 3;
#pragma unroll
                for (int reg = 0; reg < 4; reg++) {
                    int p = 16 * w + (lane >> 4) * 4 + reg;
                    int n = n0 + p;
                    if (n < NN) dstp[(size_t)(n * RR + r) * 4 + h] = acc[reg];
                }
            }
        }
    }
    __syncthreads();
    for (int v = tid; v < 2048; v += 256) {
        int row = v >> 5, c4 = (v & 31) * 4, n = n0 + row;
        if (n < NN) {
            float4 hv = *(const float4*)&Os[row * 132 + c4];
            ushort4 o = {f2us(hv.x), f2us(hv.y), f2us(hv.z), f2us(hv.w)};
            *(ushort4*)((u16*)xw + (size_t)(n * RR + r) * HIDC + c4) = o;
        }
    }
}

// ---------------- fused attention: softmax over CSR edges + aggregate + bias/ReLU/LN ----------------
__global__ __launch_bounds__(256) void k_attn(const int* __restrict__ rowptr,
                                              const int* __restrict__ elist,
                                              const int* __restrict__ ei,
                                              const int* __restrict__ et,
                                              const float* __restrict__ sb,
                                              const float* __restrict__ tb,
                                              const bf16* __restrict__ xw,
                                              const void* __restrict__ b,
                                              const void* __restrict__ g,
                                              const void* __restrict__ bb,
                                              const float* __restrict__ hprev,
                                              float* __restrict__ hout,
                                              const int* __restrict__ fl) {
    const int lane = threadIdx.x & 63;
    const int d = blockIdx.x * 4 + (threadIdx.x >> 6);
    if (d >= NN) return;
    const bool f = fl[0] != 0;
    const int hl = lane >> 4;
    const int start = rowptr[d], end = rowptr[d + 1];
    float m0 = -1e30f, m1 = -1e30f, m2 = -1e30f, m3 = -1e30f;
    float l0 = 0.f, l1 = 0.f, l2 = 0.f, l3 = 0.f;
    float acc0 = 0.f, acc1 = 0.f;
    for (int c0 = start; c0 < end; c0 += 64) {
        int n = end - c0;
        if (n > 64) n = 64;
        float a0, a1, a2, a3;
        int sr = 0;
        if (lane < n) {
            int e = elist[c0 + lane];
            int src = ei[e], r = et[e];
            sr = src * RR + r;
            float4 si = *(const float4*)&sb[(size_t)(d * RR + r) * 4];
            float4 tj = *(const float4*)&tb[(size_t)sr * 4];
            a0 = si.x + tj.x; a0 = a0 >= 0.f ? a0 : 0.2f * a0;
            a1 = si.y + tj.y; a1 = a1 >= 0.f ? a1 : 0.2f * a1;
            a2 = si.z + tj.z; a2 = a2 >= 0.f ? a2 : 0.2f * a2;
            a3 = si.w + tj.w; a3 = a3 >= 0.f ? a3 : 0.2f * a3;
        } else { a0 = a1 = a2 = a3 = -1e30f; }
        float n0 = fmaxf(m0, wredmax(a0));
        float n1 = fmaxf(m1, wredmax(a1));
        float n2 = fmaxf(m2, wredmax(a2));
        float n3 = fmaxf(m3, wredmax(a3));
        float s0 = __expf(m0 - n0), s1 = __expf(m1 - n1);
        float s2 = __expf(m2 - n2), s3 = __expf(m3 - n3);
        float e0 = __expf(a0 - n0), e1 = __expf(a1 - n1);
        float e2 = __expf(a2 - n2), e3 = __expf(a3 - n3);
        l0 = l0 * s0 + wredsum(e0);
        l1 = l1 * s1 + wredsum(e1);
        l2 = l2 * s2 + wredsum(e2);
        l3 = l3 * s3 + wredsum(e3);
        float scl = hl == 0 ? s0 : hl == 1 ? s1 : hl == 2 ? s2 : s3;
        acc0 *= scl; acc1 *= scl;
        for (int j = 0; j < n; j++) {
            int srj = __shfl(sr, j);
            float wx = __shfl(e0, j), wy = __shfl(e1, j);
            float wz = __shfl(e2, j), ww = __shfl(e3, j);
            float wgt = hl == 0 ? wx : hl == 1 ? wy : hl == 2 ? wz : ww;
            ushort2 uv = *(const ushort2*)((const u16*)xw + (size_t)srj * HIDC + lane * 2);
            acc0 += wgt * us2f(uv.x);
            acc1 += wgt * us2f(uv.y);
        }
        m0 = n0; m1 = n1; m2 = n2; m3 = n3;
    }
    float ld = hl == 0 ? l0 : hl == 1 ? l1 : hl == 2 ? l2 : l3;
    float inv = 1.f / (ld + 1e-16f);
    float v0 = acc0 * inv + ldf(b, 2 * lane, f);
    float v1 = acc1 * inv + ldf(b, 2 * lane + 1, f);
    v0 = fmaxf(v0, 0.f);
    v1 = fmaxf(v1, 0.f);
    float mean = wredsum(v0 + v1) * (1.f / 128.f);
    float d0 = v0 - mean, d1 = v1 - mean;
    float rstd = rsqrtf(wredsum(d0 * d0 + d1 * d1) * (1.f / 128.f) + 1e-5f);
    float y0 = d0 * rstd * ldf(g, 2 * lane, f) + ldf(bb, 2 * lane, f);
    float y1 = d1 * rstd * ldf(g, 2 * lane + 1, f) + ldf(bb, 2 * lane + 1, f);
    if (hprev) {
        y0 += hprev[(size_t)d * HIDC + 2 * lane];
        y1 += hprev[(size_t)d * HIDC + 2 * lane + 1];
    }
    *(float2*)&hout[(size_t)d * HIDC + 2 * lane] = float2{y0, y1};
}

// ---------------- mw1 -> B-fragment order (bf16) for MFMA decode ----------------
__global__ void k_dswz(const void* __restrict__ mw1, u16* __restrict__ Wf,
                       const int* __restrict__ fl) {
    int idx = blockIdx.x * 256 + threadIdx.x;  // 0..4095
    if (idx >= 4096) return;
    const bool f = fl[0] != 0;
    int c = idx >> 9, q = (idx >> 6) & 7, ln = idx & 63;
    int k0 = q * 32 + (ln >> 4) * 8;
    int nn = c * 16 + (ln & 15);
    u16 o[8];
#pragma unroll
    for (int j = 0; j < 8; j++) {
        float v = ldf(mw1, (k0 + j) * HIDC + nn, f);
        o[j] = f2us(v);
    }
    *(ushort4*)&Wf[idx * 8]     = ushort4{o[0], o[1], o[2], o[3]};
    *(ushort4*)&Wf[idx * 8 + 4] = ushort4{o[4], o[5], o[6], o[7]};
}

// ---------------- decode (MFMA) ----------------
__global__ __launch_bounds__(256) void k_decode2(const float* __restrict__ h,
                                                 const int* __restrict__ edges,
                                                 const u16* __restrict__ Wf,
                                                 const void* __restrict__ mb1,
                                                 const void* __restrict__ mw2,
                                                 const void* __restrict__ mb2,
                                                 void* __restrict__ out,
                                                 const int* __restrict__ fl) {
    __shared__ u16 AshU[64 * 264];
    __shared__ float w2s[HIDC * NCL];
    __shared__ float mb2s[NCL];
    const int tid = threadIdx.x;
    const bool f = fl[0] != 0;
    const int p0 = blockIdx.x * 64;
    for (int v = tid; v < HIDC * NCL; v += 256) w2s[v] = ldf(mw2, v, f);
    if (tid < NCL) mb2s[tid] = ldf(mb2, tid, f);
    for (int v = tid; v < 4096; v += 256) {
        int p = v >> 6, ch = v & 63;
        int half = ch >> 5, cc = (ch & 31) * 4;
        int node = edges[(size_t)(p0 + p) * 2 + half];
        float4 hv = *(const float4*)&h[(size_t)node * HIDC + cc];
        ushort4 o = {f2us(hv.x), f2us(hv.y), f2us(hv.z), f2us(hv.w)};
        *(ushort4*)&AshU[p * 264 + half * HIDC + cc] = o;
    }
    __syncthreads();
    const int w = tid >> 6, lane = tid & 63;
    short8 af[8];
#pragma unroll
    for (int q = 0; q < 8; q++)
        af[q] = *(const short8*)&AshU[(16 * w + (lane & 15)) * 264 + q * 32 + (lane >> 4) * 8];
    __syncthreads();
    float* zsf = (float*)AshU;  // [64][132]
#pragma unroll
    for (int c = 0; c < 8; c++) {
        floatx4 acc = {0.f, 0.f, 0.f, 0.f};
#pragma unroll
        for (int q = 0; q < 8; q++) {
            short8 bfr = *(const short8*)&Wf[(size_t)(((c * 8 + q) * 64 + lane) * 8)];
            acc = __builtin_amdgcn_mfma_f32_16x16x32_bf16(af[q], bfr, acc, 0, 0, 0);
        }
        int col = c * 16 + (lane & 15);
        float bv = ldf(mb1, col, f);
#pragma unroll
        for (int reg = 0; reg < 4; reg++) {
            int p = 16 * w + (lane >> 4) * 4 + reg;
            float z = acc[reg] + bv;
            zsf[p * 132 + col] = 0.5f * z * (1.f + erff(z * 0.70710678118654752f));
        }
    }
    __syncthreads();
    for (int o = tid; o < 512; o += 256) {
        int p = o >> 3, cc = o & 7;
        float sv = mb2s[cc];
        for (int j = 0; j < HIDC; j++) sv += zsf[p * 132 + j] * w2s[j * NCL + cc];
        size_t oi = (size_t)(p0 + p) * NCL + cc;
        if (f) ((float*)out)[oi] = sv;
        else   ((bf16*)out)[oi] = __float2bfloat16(sv);
    }
}

extern "C" void kernel_launch(void* const* d_in, const int* in_sizes, int n_in,
                              void* d_out, int out_size, void* d_ws, size_t ws_size,
                              hipStream_t stream) {
    (void)in_sizes; (void)n_in; (void)out_size; (void)ws_size;
    const void* x    = d_in[0];
    const int* ei    = (const int*)d_in[1];
    const int* et    = (const int*)d_in[2];
    const int* edges = (const int*)d_in[3];
    const void* w1 = d_in[4];
    const void* q1 = d_in[5];
    const void* k1 = d_in[6];
    const void* b1 = d_in[7];
    const void* w2 = d_in[8];
    const void* q2 = d_in[9];
    const void* k2 = d_in[10];
    const void* b2 = d_in[11];
    const void* ln1g = d_in[12];
    const void* ln1b = d_in[13];
    const void* ln2g = d_in[14];
    const void* ln2b = d_in[15];
    const void* mw1 = d_in[16];
    const void* mb1 = d_in[17];
    const void* mw2 = d_in[18];
    const void* mb2 = d_in[19];

    // workspace layout — within round-3-proven bound (<= 169,425,560 B)
    char* ws = (char*)d_ws;
    bf16* xwb   = (bf16*)ws;                      // [0, 102,400,000)
    u16* Wf     = (u16*)ws;                       // ALIAS xwb: k_dswz runs after last xwb read
    float* sbuf = (float*)(ws + 102400000);       // 6.4 MB
    float* tbuf = (float*)(ws + 108800000);       // 6.4 MB
    float* h1   = (float*)(ws + 115200000);       // 25.6 MB
    float* hsum = (float*)(ws + 140800000);       // 25.6 MB
    u16* Wf2    = (u16*)(ws + 140800000);         // ALIAS hsum: dead before hsum is written (589,824 B)
    int* rowptr = (int*)(ws + 166400000);         // NN+1 ints
    int* cursor = (int*)(ws + 166600016);         // NN ints
    int* elist  = (int*)(ws + 166800016);         // EE ints
    float* qkw  = (float*)(ws + 169360016);       // 65,536 B -> ends 169,425,552
    int* flags  = (int*)(ws + 169425552);         // 8 B -> ends 169,425,560 (proven)

    k_sniff<<<1, 256, 0, stream>>>((const u16*)x, flags);

    // CSR build + weight preprocessing
    k_zero<<<196, 256, 0, stream>>>(cursor, NN);
    k_hist<<<2500, 256, 0, stream>>>(ei, cursor);
    k_scan<<<1, 1024, 0, stream>>>(cursor, rowptr);
    k_scatter<<<2500, 256, 0, stream>>>(ei, cursor, elist);
    k_qkw<<<64, 256, 0, stream>>>(w1, w2, q1, k1, q2, k2, qkw, flags);
    k_wswz<<<144, 256, 0, stream>>>(w1, w2, qkw, Wf2, flags);

    for (int layer = 0; layer < 2; ++layer) {
        const void* b  = layer ? b2 : b1;
        const void* lg = layer ? ln2g : ln1g;
        const void* lb = layer ? ln2b : ln1b;
        k_xw2<<<dim3(782, 8), 256, 0, stream>>>(layer ? (const void*)h1 : x, Wf2, xwb,
                                                sbuf, tbuf,
                                                layer ? flags + 1 : flags, layer);
        k_attn<<<12500, 256, 0, stream>>>(rowptr, elist, ei, et, sbuf, tbuf, xwb,
                                          b, lg, lb,
                                          layer ? h1 : (const float*)nullptr,
                                          layer ? hsum : h1, flags);
    }
    // decode weight swizzle into xwb space (xwb dead after attn L1)
    k_dswz<<<16, 256, 0, stream>>>(mw1, Wf, flags);
    k_decode2<<<3125, 256, 0, stream>>>(hsum, edges, Wf, mb1, mw2, mb2, d_out, flags);
}

// Round 8
// 713.114 us; speedup vs baseline: 4.7569x; 1.1922x over previous
//
#include <hip/hip_runtime.h>
#include <hip/hip_bf16.h>

#define NN    50000
#define RR    8
#define HIDC  128
#define NHEADS 4
#define EE    640000
#define EE2   200000
#define NCL   8

typedef __hip_bfloat16 bf16;
typedef unsigned short u16;
typedef __attribute__((ext_vector_type(8))) short short8;
typedef __attribute__((ext_vector_type(4))) float floatx4;

__device__ __forceinline__ float us2f(u16 u) {
    return __uint_as_float(((unsigned)u) << 16);
}
__device__ __forceinline__ float bf2f(bf16 v) { return __bfloat162float(v); }
__device__ __forceinline__ u16 f2us(float f) {
    bf16 h = __float2bfloat16(f);
    return *(u16*)&h;
}
__device__ __forceinline__ float ldf(const void* p, int i, bool f32) {
    return f32 ? ((const float*)p)[i] : us2f(((const u16*)p)[i]);
}
__device__ __forceinline__ float wredmax(float v) {
#pragma unroll
    for (int off = 32; off; off >>= 1) v = fmaxf(v, __shfl_xor(v, off));
    return v;
}
__device__ __forceinline__ float wredsum(float v) {
#pragma unroll
    for (int off = 32; off; off >>= 1) v += __shfl_xor(v, off);
    return v;
}

// ---------------- dtype sniff: fp32 data viewed as bf16 has exp==0xFF hits ----------------
// 1024 threads, ushort8 vector loads over 64K u16 (128 KB). fp32 -> ~128 hits, bf16 -> 0.
__global__ __launch_bounds__(1024) void k_sniff(const u16* __restrict__ x, int* __restrict__ flags) {
    __shared__ int cnt;
    if (threadIdx.x == 0) cnt = 0;
    __syncthreads();
    int c = 0;
#pragma unroll
    for (int it = 0; it < 8; it++) {
        ushort4 a = ((const ushort4*)x)[(it * 1024 + threadIdx.x) * 2];
        ushort4 b = ((const ushort4*)x)[(it * 1024 + threadIdx.x) * 2 + 1];
        c += (((a.x >> 7) & 0xFF) == 0xFF) + (((a.y >> 7) & 0xFF) == 0xFF)
           + (((a.z >> 7) & 0xFF) == 0xFF) + (((a.w >> 7) & 0xFF) == 0xFF)
           + (((b.x >> 7) & 0xFF) == 0xFF) + (((b.y >> 7) & 0xFF) == 0xFF)
           + (((b.z >> 7) & 0xFF) == 0xFF) + (((b.w >> 7) & 0xFF) == 0xFF);
    }
    c += __shfl_xor(c, 32); c += __shfl_xor(c, 16); c += __shfl_xor(c, 8);
    c += __shfl_xor(c, 4);  c += __shfl_xor(c, 2);  c += __shfl_xor(c, 1);
    if ((threadIdx.x & 63) == 0) atomicAdd(&cnt, c);
    __syncthreads();
    if (threadIdx.x == 0) { flags[0] = (cnt > 16) ? 1 : 0; flags[1] = 1; }
}

// ---------------- CSR build ----------------
__global__ void k_zero(int* __restrict__ p, int n) {
    int i = blockIdx.x * 256 + threadIdx.x;
    if (i < n) p[i] = 0;
}
__global__ void k_hist(const int* __restrict__ ei, int* __restrict__ deg) {
    int e = blockIdx.x * 256 + threadIdx.x;
    if (e < EE) atomicAdd(&deg[ei[EE + e]], 1);
}
__global__ __launch_bounds__(1024) void k_scan(int* __restrict__ deg,
                                               int* __restrict__ rowptr) {
    __shared__ int part[1024];
    const int t = threadIdx.x;
    const int CH = 49;
    int lo = t * CH, hi = lo + CH;
    if (hi > NN) hi = NN;
    if (lo > NN) lo = NN;
    int base = 0;
    for (int i = lo; i < hi; i++) base += deg[i];
    part[t] = base;
    __syncthreads();
    for (int off = 1; off < 1024; off <<= 1) {
        int v = (t >= off) ? part[t - off] : 0;
        __syncthreads();
        part[t] += v;
        __syncthreads();
    }
    int excl = (t == 0) ? 0 : part[t - 1];
    for (int i = lo; i < hi; i++) {
        int dv = deg[i];
        rowptr[i] = excl;
        deg[i] = excl;
        excl += dv;
    }
    if (t == 1023) rowptr[NN] = part[1023];
}
__global__ void k_scatter(const int* __restrict__ ei, int* __restrict__ cursor,
                          int* __restrict__ elist) {
    int e = blockIdx.x * 256 + threadIdx.x;
    if (e >= EE) return;
    int pos = atomicAdd(&cursor[ei[EE + e]], 1);
    elist[pos] = e;
}

// ---------------- qkw[mat][i][h8] = sum_o W[r][i][o] * (q|k)[o][h] ----------------
// mat 0..7 = layer0 rel r, 8..15 = layer1; h8 0..3 -> q heads, 4..7 -> k heads
__global__ void k_qkw(const void* __restrict__ w1, const void* __restrict__ w2,
                      const void* __restrict__ q1, const void* __restrict__ k1,
                      const void* __restrict__ q2, const void* __restrict__ k2,
                      float* __restrict__ qkw, const int* __restrict__ fl) {
    int idx = blockIdx.x * 256 + threadIdx.x;  // 16*128*8 = 16384
    if (idx >= 16384) return;
    const bool f = fl[0] != 0;
    int mat = idx >> 10;
    int i   = (idx >> 3) & 127;
    int h8  = idx & 7;
    const void* W = (mat >= 8) ? w2 : w1;
    const void* qk = (mat >= 8) ? ((h8 < 4) ? q2 : k2) : ((h8 < 4) ? q1 : k1);
    int h = h8 & 3;
    int r = mat & 7;
    float acc = 0.f;
    for (int o = 0; o < HIDC; o++)
        acc += ldf(W, (r * HIDC + i) * HIDC + o, f) * ldf(qk, o * NHEADS + h, f);
    qkw[idx] = acc;
}

// ---------------- W (+qkw cols) -> MFMA B-fragment order: 9 col-tiles ----------------
__global__ void k_wswz(const void* __restrict__ w1, const void* __restrict__ w2,
                       const float* __restrict__ qkw,
                       u16* __restrict__ Wf2, const int* __restrict__ fl) {
    int idx = blockIdx.x * 256 + threadIdx.x;  // 16 * 2304 = 36864
    if (idx >= 36864) return;
    const bool f = fl[0] != 0;
    int mat = idx / 2304, rest = idx % 2304;
    int c = rest >> 8, q = (rest >> 6) & 3, ln = rest & 63;
    int k0 = q * 32 + (ln >> 4) * 8;
    int nn = c * 16 + (ln & 15);
    int r = mat & 7;
    u16 o[8];
    if (c < 8) {
        const void* W = (mat >= 8) ? w2 : w1;
#pragma unroll
        for (int j = 0; j < 8; j++)
            o[j] = f2us(ldf(W, (r * HIDC + k0 + j) * HIDC + nn, f));
    } else {
        int col = nn - 128;  // 0..15
#pragma unroll
        for (int j = 0; j < 8; j++)
            o[j] = (col < 8) ? f2us(qkw[mat * 1024 + (k0 + j) * 8 + col]) : (u16)0;
    }
    u16* dst = Wf2 + (size_t)mat * 18432 + (size_t)(((c * 4 + q) * 64 + ln) * 8);
    *(ushort4*)dst       = ushort4{o[0], o[1], o[2], o[3]};
    *(ushort4*)(dst + 4) = ushort4{o[4], o[5], o[6], o[7]};
}

// ---------------- MFMA xw + s/t from col-tile 8 ----------------
__global__ __launch_bounds__(256) void k_xw2(const void* __restrict__ X,
                                             const u16* __restrict__ Wf2,
                                             bf16* __restrict__ xw,
                                             float* __restrict__ sbuf,
                                             float* __restrict__ tbuf,
                                             const int* __restrict__ fx,
                                             int layer) {
    __shared__ u16 Xs[64 * 136];    // 17.4 KB bf16 input tile
    __shared__ float Os[64 * 132];  // 33.8 KB fp32 output tile
    const int tid = threadIdx.x;
    const int r = blockIdx.y;
    const int n0 = blockIdx.x * 64;
    const bool xf = fx[0] != 0;
    for (int v = tid; v < 2048; v += 256) {
        int row = v >> 5, c4 = (v & 31) * 4, n = n0 + row;
        ushort4 o = {0, 0, 0, 0};
        if (n < NN) {
            if (xf) {
                float4 hv = *(const float4*)((const float*)X + (size_t)n * HIDC + c4);
                o = ushort4{f2us(hv.x), f2us(hv.y), f2us(hv.z), f2us(hv.w)};
            } else {
                o = *(const ushort4*)((const u16*)X + (size_t)n * HIDC + c4);
            }
        }
        *(ushort4*)&Xs[row * 136 + c4] = o;
    }
    __syncthreads();
    const int w = tid >> 6, lane = tid & 63;
    short8 af[4];
#pragma unroll
    for (int q = 0; q < 4; q++)
        af[q] = *(const short8*)&Xs[(16 * w + (lane & 15)) * 136 + q * 32 + (lane >> 4) * 8];
    const u16* Wfr = Wf2 + (size_t)(layer * 8 + r) * 18432;
#pragma unroll
    for (int c = 0; c < 9; c++) {
        floatx4 acc = {0.f, 0.f, 0.f, 0.f};
#pragma unroll
        for (int q = 0; q < 4; q++) {
            short8 bfr = *(const short8*)&Wfr[(size_t)(((c * 4 + q) * 64 + lane) * 8)];
            acc = __builtin_amdgcn_mfma_f32_16x16x32_bf16(af[q], bfr, acc, 0, 0, 0);
        }
        if (c < 8) {
            int col = c * 16 + (lane & 15);
#pragma unroll
            for (int reg = 0; reg < 4; reg++) {
                int p = 16 * w + (lane >> 4) * 4 + reg;
                Os[p * 132 + col] = acc[reg];
            }
        } else {
            int cl = lane & 15;  // 0..3 -> s heads, 4..7 -> t heads
            if (cl < 8) {
                float* dstp = (cl < 4) ? sbuf : tbuf;
                int h = cl & 3;
#pragma unroll
                for (int reg = 0; reg < 4; reg++) {
                    int p = 16 * w + (lane >> 4) * 4 + reg;
                    int n = n0 + p;
                    if (n < NN) dstp[(size_t)(n * RR + r) * 4 + h] = acc[reg];
                }
            }
        }
    }
    __syncthreads();
    for (int v = tid; v < 2048; v += 256) {
        int row = v >> 5, c4 = (v & 31) * 4, n = n0 + row;
        if (n < NN) {
            float4 hv = *(const float4*)&Os[row * 132 + c4];
            ushort4 o = {f2us(hv.x), f2us(hv.y), f2us(hv.z), f2us(hv.w)};
            *(ushort4*)((u16*)xw + (size_t)(n * RR + r) * HIDC + c4) = o;
        }
    }
}

// ---------------- fused attention: softmax over CSR edges + aggregate + bias/ReLU/LN ----------------
__global__ __launch_bounds__(256) void k_attn(const int* __restrict__ rowptr,
                                              const int* __restrict__ elist,
                                              const int* __restrict__ ei,
                                              const int* __restrict__ et,
                                              const float* __restrict__ sb,
                                              const float* __restrict__ tb,
                                              const bf16* __restrict__ xw,
                                              const void* __restrict__ b,
                                              const void* __restrict__ g,
                                              const void* __restrict__ bb,
                                              const float* __restrict__ hprev,
                                              float* __restrict__ hout,
                                              const int* __restrict__ fl) {
    const int lane = threadIdx.x & 63;
    const int d = blockIdx.x * 4 + (threadIdx.x >> 6);
    if (d >= NN) return;
    const bool f = fl[0] != 0;
    const int hl = lane >> 4;
    const int start = rowptr[d], end = rowptr[d + 1];
    float m0 = -1e30f, m1 = -1e30f, m2 = -1e30f, m3 = -1e30f;
    float l0 = 0.f, l1 = 0.f, l2 = 0.f, l3 = 0.f;
    float acc0 = 0.f, acc1 = 0.f;
    for (int c0 = start; c0 < end; c0 += 64) {
        int n = end - c0;
        if (n > 64) n = 64;
        float a0, a1, a2, a3;
        int sr = 0;
        if (lane < n) {
            int e = elist[c0 + lane];
            int src = ei[e], r = et[e];
            sr = src * RR + r;
            float4 si = *(const float4*)&sb[(size_t)(d * RR + r) * 4];
            float4 tj = *(const float4*)&tb[(size_t)sr * 4];
            a0 = si.x + tj.x; a0 = a0 >= 0.f ? a0 : 0.2f * a0;
            a1 = si.y + tj.y; a1 = a1 >= 0.f ? a1 : 0.2f * a1;
            a2 = si.z + tj.z; a2 = a2 >= 0.f ? a2 : 0.2f * a2;
            a3 = si.w + tj.w; a3 = a3 >= 0.f ? a3 : 0.2f * a3;
        } else { a0 = a1 = a2 = a3 = -1e30f; }
        float n0 = fmaxf(m0, wredmax(a0));
        float n1 = fmaxf(m1, wredmax(a1));
        float n2 = fmaxf(m2, wredmax(a2));
        float n3 = fmaxf(m3, wredmax(a3));
        float s0 = __expf(m0 - n0), s1 = __expf(m1 - n1);
        float s2 = __expf(m2 - n2), s3 = __expf(m3 - n3);
        float e0 = __expf(a0 - n0), e1 = __expf(a1 - n1);
        float e2 = __expf(a2 - n2), e3 = __expf(a3 - n3);
        l0 = l0 * s0 + wredsum(e0);
        l1 = l1 * s1 + wredsum(e1);
        l2 = l2 * s2 + wredsum(e2);
        l3 = l3 * s3 + wredsum(e3);
        float scl = hl == 0 ? s0 : hl == 1 ? s1 : hl == 2 ? s2 : s3;
        acc0 *= scl; acc1 *= scl;
        for (int j = 0; j < n; j++) {
            int srj = __shfl(sr, j);
            float wx = __shfl(e0, j), wy = __shfl(e1, j);
            float wz = __shfl(e2, j), ww = __shfl(e3, j);
            float wgt = hl == 0 ? wx : hl == 1 ? wy : hl == 2 ? wz : ww;
            ushort2 uv = *(const ushort2*)((const u16*)xw + (size_t)srj * HIDC + lane * 2);
            acc0 += wgt * us2f(uv.x);
            acc1 += wgt * us2f(uv.y);
        }
        m0 = n0; m1 = n1; m2 = n2; m3 = n3;
    }
    float ld = hl == 0 ? l0 : hl == 1 ? l1 : hl == 2 ? l2 : l3;
    float inv = 1.f / (ld + 1e-16f);
    float v0 = acc0 * inv + ldf(b, 2 * lane, f);
    float v1 = acc1 * inv + ldf(b, 2 * lane + 1, f);
    v0 = fmaxf(v0, 0.f);
    v1 = fmaxf(v1, 0.f);
    float mean = wredsum(v0 + v1) * (1.f / 128.f);
    float d0 = v0 - mean, d1 = v1 - mean;
    float rstd = rsqrtf(wredsum(d0 * d0 + d1 * d1) * (1.f / 128.f) + 1e-5f);
    float y0 = d0 * rstd * ldf(g, 2 * lane, f) + ldf(bb, 2 * lane, f);
    float y1 = d1 * rstd * ldf(g, 2 * lane + 1, f) + ldf(bb, 2 * lane + 1, f);
    if (hprev) {
        y0 += hprev[(size_t)d * HIDC + 2 * lane];
        y1 += hprev[(size_t)d * HIDC + 2 * lane + 1];
    }
    *(float2*)&hout[(size_t)d * HIDC + 2 * lane] = float2{y0, y1};
}

// ---------------- mw1 -> B-fragment order (bf16) for MFMA decode ----------------
__global__ void k_dswz(const void* __restrict__ mw1, u16* __restrict__ Wf,
                       const int* __restrict__ fl) {
    int idx = blockIdx.x * 256 + threadIdx.x;  // 0..4095
    if (idx >= 4096) return;
    const bool f = fl[0] != 0;
    int c = idx >> 9, q = (idx >> 6) & 7, ln = idx & 63;
    int k0 = q * 32 + (ln >> 4) * 8;
    int nn = c * 16 + (ln & 15);
    u16 o[8];
#pragma unroll
    for (int j = 0; j < 8; j++) {
        float v = ldf(mw1, (k0 + j) * HIDC + nn, f);
        o[j] = f2us(v);
    }
    *(ushort4*)&Wf[idx * 8]     = ushort4{o[0], o[1], o[2], o[3]};
    *(ushort4*)&Wf[idx * 8 + 4] = ushort4{o[4], o[5], o[6], o[7]};
}

// ---------------- decode (MFMA) ----------------
__global__ __launch_bounds__(256) void k_decode2(const float* __restrict__ h,
                                                 const int* __restrict__ edges,
                                                 const u16* __restrict__ Wf,
                                                 const void* __restrict__ mb1,
                                                 const void* __restrict__ mw2,
                                                 const void* __restrict__ mb2,
                                                 void* __restrict__ out,
                                                 const int* __restrict__ fl) {
    __shared__ u16 AshU[64 * 264];
    __shared__ float w2s[HIDC * NCL];
    __shared__ float mb2s[NCL];
    const int tid = threadIdx.x;
    const bool f = fl[0] != 0;
    const int p0 = blockIdx.x * 64;
    for (int v = tid; v < HIDC * NCL; v += 256) w2s[v] = ldf(mw2, v, f);
    if (tid < NCL) mb2s[tid] = ldf(mb2, tid, f);
    for (int v = tid; v < 4096; v += 256) {
        int p = v >> 6, ch = v & 63;
        int half = ch >> 5, cc = (ch & 31) * 4;
        int node = edges[(size_t)(p0 + p) * 2 + half];
        float4 hv = *(const float4*)&h[(size_t)node * HIDC + cc];
        ushort4 o = {f2us(hv.x), f2us(hv.y), f2us(hv.z), f2us(hv.w)};
        *(ushort4*)&AshU[p * 264 + half * HIDC + cc] = o;
    }
    __syncthreads();
    const int w = tid >> 6, lane = tid & 63;
    short8 af[8];
#pragma unroll
    for (int q = 0; q < 8; q++)
        af[q] = *(const short8*)&AshU[(16 * w + (lane & 15)) * 264 + q * 32 + (lane >> 4) * 8];
    __syncthreads();
    float* zsf = (float*)AshU;  // [64][132]
#pragma unroll
    for (int c = 0; c < 8; c++) {
        floatx4 acc = {0.f, 0.f, 0.f, 0.f};
#pragma unroll
        for (int q = 0; q < 8; q++) {
            short8 bfr = *(const short8*)&Wf[(size_t)(((c * 8 + q) * 64 + lane) * 8)];
            acc = __builtin_amdgcn_mfma_f32_16x16x32_bf16(af[q], bfr, acc, 0, 0, 0);
        }
        int col = c * 16 + (lane & 15);
        float bv = ldf(mb1, col, f);
#pragma unroll
        for (int reg = 0; reg < 4; reg++) {
            int p = 16 * w + (lane >> 4) * 4 + reg;
            float z = acc[reg] + bv;
            zsf[p * 132 + col] = 0.5f * z * (1.f + erff(z * 0.70710678118654752f));
        }
    }
    __syncthreads();
    for (int o = tid; o < 512; o += 256) {
        int p = o >> 3, cc = o & 7;
        float sv = mb2s[cc];
        for (int j = 0; j < HIDC; j++) sv += zsf[p * 132 + j] * w2s[j * NCL + cc];
        size_t oi = (size_t)(p0 + p) * NCL + cc;
        if (f) ((float*)out)[oi] = sv;
        else   ((bf16*)out)[oi] = __float2bfloat16(sv);
    }
}

extern "C" void kernel_launch(void* const* d_in, const int* in_sizes, int n_in,
                              void* d_out, int out_size, void* d_ws, size_t ws_size,
                              hipStream_t stream) {
    (void)in_sizes; (void)n_in; (void)out_size; (void)ws_size;
    const void* x    = d_in[0];
    const int* ei    = (const int*)d_in[1];
    const int* et    = (const int*)d_in[2];
    const int* edges = (const int*)d_in[3];
    const void* w1 = d_in[4];
    const void* q1 = d_in[5];
    const void* k1 = d_in[6];
    const void* b1 = d_in[7];
    const void* w2 = d_in[8];
    const void* q2 = d_in[9];
    const void* k2 = d_in[10];
    const void* b2 = d_in[11];
    const void* ln1g = d_in[12];
    const void* ln1b = d_in[13];
    const void* ln2g = d_in[14];
    const void* ln2b = d_in[15];
    const void* mw1 = d_in[16];
    const void* mb1 = d_in[17];
    const void* mw2 = d_in[18];
    const void* mb2 = d_in[19];

    // workspace layout — within round-3-proven bound (<= 169,425,560 B)
    char* ws = (char*)d_ws;
    bf16* xwb   = (bf16*)ws;                      // [0, 102,400,000)
    u16* Wf     = (u16*)ws;                       // ALIAS xwb: k_dswz runs after last xwb read
    float* sbuf = (float*)(ws + 102400000);       // 6.4 MB
    float* tbuf = (float*)(ws + 108800000);       // 6.4 MB
    float* h1   = (float*)(ws + 115200000);       // 25.6 MB
    float* hsum = (float*)(ws + 140800000);       // 25.6 MB
    u16* Wf2    = (u16*)(ws + 140800000);         // ALIAS hsum: dead before hsum is written (589,824 B)
    int* rowptr = (int*)(ws + 166400000);         // NN+1 ints
    int* cursor = (int*)(ws + 166600016);         // NN ints
    int* elist  = (int*)(ws + 166800016);         // EE ints
    float* qkw  = (float*)(ws + 169360016);       // 65,536 B -> ends 169,425,552
    int* flags  = (int*)(ws + 169425552);         // 8 B -> ends 169,425,560 (proven)

    k_sniff<<<1, 1024, 0, stream>>>((const u16*)x, flags);

    // CSR build + weight preprocessing
    k_zero<<<196, 256, 0, stream>>>(cursor, NN);
    k_hist<<<2500, 256, 0, stream>>>(ei, cursor);
    k_scan<<<1, 1024, 0, stream>>>(cursor, rowptr);
    k_scatter<<<2500, 256, 0, stream>>>(ei, cursor, elist);
    k_qkw<<<64, 256, 0, stream>>>(w1, w2, q1, k1, q2, k2, qkw, flags);
    k_wswz<<<144, 256, 0, stream>>>(w1, w2, qkw, Wf2, flags);

    for (int layer = 0; layer < 2; ++layer) {
        const void* b  = layer ? b2 : b1;
        const void* lg = layer ? ln2g : ln1g;
        const void* lb = layer ? ln2b : ln1b;
        k_xw2<<<dim3(782, 8), 256, 0, stream>>>(layer ? (const void*)h1 : x, Wf2, xwb,
                                                sbuf, tbuf,
                                                layer ? flags + 1 : flags, layer);
        k_attn<<<12500, 256, 0, stream>>>(rowptr, elist, ei, et, sbuf, tbuf, xwb,
                                          b, lg, lb,
                                          layer ? h1 : (const float*)nullptr,
                                          layer ? hsum : h1, flags);
    }
    // decode weight swizzle into xwb space (xwb dead after attn L1)
    k_dswz<<<16, 256, 0, stream>>>(mw1, Wf, flags);
    k_decode2<<<3125, 256, 0, stream>>>(hsum, edges, Wf, mb1, mw2, mb2, d_out, flags);
}

// Round 9
// 686.621 us; speedup vs baseline: 4.9405x; 1.0386x over previous
//
#include <hip/hip_runtime.h>
#include <hip/hip_bf16.h>

#define NN    50000
#define RR    8
#define HIDC  128
#define NHEADS 4
#define EE    640000
#define EE2   200000
#define NCL   8

typedef __hip_bfloat16 bf16;
typedef unsigned short u16;
typedef __attribute__((ext_vector_type(8))) short short8;
typedef __attribute__((ext_vector_type(4))) float floatx4;

__device__ __forceinline__ float us2f(u16 u) {
    return __uint_as_float(((unsigned)u) << 16);
}
__device__ __forceinline__ float bf2f(bf16 v) { return __bfloat162float(v); }
__device__ __forceinline__ u16 f2us(float f) {
    bf16 h = __float2bfloat16(f);
    return *(u16*)&h;
}
__device__ __forceinline__ float ldf(const void* p, int i, bool f32) {
    return f32 ? ((const float*)p)[i] : us2f(((const u16*)p)[i]);
}
__device__ __forceinline__ float wredmax(float v) {
#pragma unroll
    for (int off = 32; off; off >>= 1) v = fmaxf(v, __shfl_xor(v, off));
    return v;
}
__device__ __forceinline__ float wredsum(float v) {
#pragma unroll
    for (int off = 32; off; off >>= 1) v += __shfl_xor(v, off);
    return v;
}

// ---------------- dtype sniff: fp32 data viewed as bf16 has exp==0xFF hits ----------------
__global__ __launch_bounds__(1024) void k_sniff(const u16* __restrict__ x, int* __restrict__ flags) {
    __shared__ int cnt;
    if (threadIdx.x == 0) cnt = 0;
    __syncthreads();
    int c = 0;
#pragma unroll
    for (int it = 0; it < 8; it++) {
        ushort4 a = ((const ushort4*)x)[(it * 1024 + threadIdx.x) * 2];
        ushort4 b = ((const ushort4*)x)[(it * 1024 + threadIdx.x) * 2 + 1];
        c += (((a.x >> 7) & 0xFF) == 0xFF) + (((a.y >> 7) & 0xFF) == 0xFF)
           + (((a.z >> 7) & 0xFF) == 0xFF) + (((a.w >> 7) & 0xFF) == 0xFF)
           + (((b.x >> 7) & 0xFF) == 0xFF) + (((b.y >> 7) & 0xFF) == 0xFF)
           + (((b.z >> 7) & 0xFF) == 0xFF) + (((b.w >> 7) & 0xFF) == 0xFF);
    }
    c += __shfl_xor(c, 32); c += __shfl_xor(c, 16); c += __shfl_xor(c, 8);
    c += __shfl_xor(c, 4);  c += __shfl_xor(c, 2);  c += __shfl_xor(c, 1);
    if ((threadIdx.x & 63) == 0) atomicAdd(&cnt, c);
    __syncthreads();
    if (threadIdx.x == 0) { flags[0] = (cnt > 16) ? 1 : 0; flags[1] = 1; }
}

// ---------------- CSR build ----------------
__global__ void k_zero(int* __restrict__ p, int n) {
    int i = blockIdx.x * 256 + threadIdx.x;
    if (i < n) p[i] = 0;
}
__global__ void k_hist(const int* __restrict__ ei, int* __restrict__ deg) {
    int e = blockIdx.x * 256 + threadIdx.x;
    if (e < EE) atomicAdd(&deg[ei[EE + e]], 1);
}
__global__ __launch_bounds__(1024) void k_scan(int* __restrict__ deg,
                                               int* __restrict__ rowptr) {
    __shared__ int part[1024];
    const int t = threadIdx.x;
    const int CH = 49;
    int lo = t * CH, hi = lo + CH;
    if (hi > NN) hi = NN;
    if (lo > NN) lo = NN;
    int base = 0;
    for (int i = lo; i < hi; i++) base += deg[i];
    part[t] = base;
    __syncthreads();
    for (int off = 1; off < 1024; off <<= 1) {
        int v = (t >= off) ? part[t - off] : 0;
        __syncthreads();
        part[t] += v;
        __syncthreads();
    }
    int excl = (t == 0) ? 0 : part[t - 1];
    for (int i = lo; i < hi; i++) {
        int dv = deg[i];
        rowptr[i] = excl;
        deg[i] = excl;
        excl += dv;
    }
    if (t == 1023) rowptr[NN] = part[1023];
}
__global__ void k_scatter(const int* __restrict__ ei, int* __restrict__ cursor,
                          int* __restrict__ elist) {
    int e = blockIdx.x * 256 + threadIdx.x;
    if (e >= EE) return;
    int pos = atomicAdd(&cursor[ei[EE + e]], 1);
    elist[pos] = e;
}

// ---------------- qkw[mat][i][h8] = sum_o W[r][i][o] * (q|k)[o][h] ----------------
__global__ void k_qkw(const void* __restrict__ w1, const void* __restrict__ w2,
                      const void* __restrict__ q1, const void* __restrict__ k1,
                      const void* __restrict__ q2, const void* __restrict__ k2,
                      float* __restrict__ qkw, const int* __restrict__ fl) {
    int idx = blockIdx.x * 256 + threadIdx.x;  // 16*128*8 = 16384
    if (idx >= 16384) return;
    const bool f = fl[0] != 0;
    int mat = idx >> 10;
    int i   = (idx >> 3) & 127;
    int h8  = idx & 7;
    const void* W = (mat >= 8) ? w2 : w1;
    const void* qk = (mat >= 8) ? ((h8 < 4) ? q2 : k2) : ((h8 < 4) ? q1 : k1);
    int h = h8 & 3;
    int r = mat & 7;
    float acc = 0.f;
    for (int o = 0; o < HIDC; o++)
        acc += ldf(W, (r * HIDC + i) * HIDC + o, f) * ldf(qk, o * NHEADS + h, f);
    qkw[idx] = acc;
}

// ---------------- W (+qkw cols) -> MFMA B-fragment order: 9 col-tiles ----------------
__global__ void k_wswz(const void* __restrict__ w1, const void* __restrict__ w2,
                       const float* __restrict__ qkw,
                       u16* __restrict__ Wf2, const int* __restrict__ fl) {
    int idx = blockIdx.x * 256 + threadIdx.x;  // 16 * 2304 = 36864
    if (idx >= 36864) return;
    const bool f = fl[0] != 0;
    int mat = idx / 2304, rest = idx % 2304;
    int c = rest >> 8, q = (rest >> 6) & 3, ln = rest & 63;
    int k0 = q * 32 + (ln >> 4) * 8;
    int nn = c * 16 + (ln & 15);
    int r = mat & 7;
    u16 o[8];
    if (c < 8) {
        const void* W = (mat >= 8) ? w2 : w1;
#pragma unroll
        for (int j = 0; j < 8; j++)
            o[j] = f2us(ldf(W, (r * HIDC + k0 + j) * HIDC + nn, f));
    } else {
        int col = nn - 128;  // 0..15
#pragma unroll
        for (int j = 0; j < 8; j++)
            o[j] = (col < 8) ? f2us(qkw[mat * 1024 + (k0 + j) * 8 + col]) : (u16)0;
    }
    u16* dst = Wf2 + (size_t)mat * 18432 + (size_t)(((c * 4 + q) * 64 + ln) * 8);
    *(ushort4*)dst       = ushort4{o[0], o[1], o[2], o[3]};
    *(ushort4*)(dst + 4) = ushort4{o[4], o[5], o[6], o[7]};
}

// ---------------- MFMA xw + s/t from col-tile 8 ----------------
__global__ __launch_bounds__(256) void k_xw2(const void* __restrict__ X,
                                             const u16* __restrict__ Wf2,
                                             bf16* __restrict__ xw,
                                             float* __restrict__ sbuf,
                                             float* __restrict__ tbuf,
                                             const int* __restrict__ fx,
                                             int layer) {
    __shared__ u16 Xs[64 * 136];    // 17.4 KB bf16 input tile
    __shared__ float Os[64 * 132];  // 33.8 KB fp32 output tile
    const int tid = threadIdx.x;
    const int r = blockIdx.y;
    const int n0 = blockIdx.x * 64;
    const bool xf = fx[0] != 0;
    for (int v = tid; v < 2048; v += 256) {
        int row = v >> 5, c4 = (v & 31) * 4, n = n0 + row;
        ushort4 o = {0, 0, 0, 0};
        if (n < NN) {
            if (xf) {
                float4 hv = *(const float4*)((const float*)X + (size_t)n * HIDC + c4);
                o = ushort4{f2us(hv.x), f2us(hv.y), f2us(hv.z), f2us(hv.w)};
            } else {
                o = *(const ushort4*)((const u16*)X + (size_t)n * HIDC + c4);
            }
        }
        *(ushort4*)&Xs[row * 136 + c4] = o;
    }
    __syncthreads();
    const int w = tid >> 6, lane = tid & 63;
    short8 af[4];
#pragma unroll
    for (int q = 0; q < 4; q++)
        af[q] = *(const short8*)&Xs[(16 * w + (lane & 15)) * 136 + q * 32 + (lane >> 4) * 8];
    const u16* Wfr = Wf2 + (size_t)(layer * 8 + r) * 18432;
#pragma unroll
    for (int c = 0; c < 9; c++) {
        floatx4 acc = {0.f, 0.f, 0.f, 0.f};
#pragma unroll
        for (int q = 0; q < 4; q++) {
            short8 bfr = *(const short8*)&Wfr[(size_t)(((c * 4 + q) * 64 + lane) * 8)];
            acc = __builtin_amdgcn_mfma_f32_16x16x32_bf16(af[q], bfr, acc, 0, 0, 0);
        }
        if (c < 8) {
            int col = c * 16 + (lane & 15);
#pragma unroll
            for (int reg = 0; reg < 4; reg++) {
                int p = 16 * w + (lane >> 4) * 4 + reg;
                Os[p * 132 + col] = acc[reg];
            }
        } else {
            int cl = lane & 15;  // 0..3 -> s heads, 4..7 -> t heads
            if (cl < 8) {
                float* dstp = (cl < 4) ? sbuf : tbuf;
                int h = cl & 3;
#pragma unroll
                for (int reg = 0; reg < 4; reg++) {
                    int p = 16 * w + (lane >> 4) * 4 + reg;
                    int n = n0 + p;
                    if (n < NN) dstp[(size_t)(n * RR + r) * 4 + h] = acc[reg];
                }
            }
        }
    }
    __syncthreads();
    for (int v = tid; v < 2048; v += 256) {
        int row = v >> 5, c4 = (v & 31) * 4, n = n0 + row;
        if (n < NN) {
            float4 hv = *(const float4*)&Os[row * 132 + c4];
            ushort4 o = {f2us(hv.x), f2us(hv.y), f2us(hv.z), f2us(hv.w)};
            *(ushort4*)((u16*)xw + (size_t)(n * RR + r) * HIDC + c4) = o;
        }
    }
}

// ---------------- fused attention: softmax over CSR edges + aggregate + bias/ReLU/LN ----------------
__global__ __launch_bounds__(256) void k_attn(const int* __restrict__ rowptr,
                                              const int* __restrict__ elist,
                                              const int* __restrict__ ei,
                                              const int* __restrict__ et,
                                              const float* __restrict__ sb,
                                              const float* __restrict__ tb,
                                              const bf16* __restrict__ xw,
                                              const void* __restrict__ b,
                                              const void* __restrict__ g,
                                              const void* __restrict__ bb,
                                              const float* __restrict__ hprev,
                                              float* __restrict__ hout,
                                              const int* __restrict__ fl) {
    const int lane = threadIdx.x & 63;
    const int d = blockIdx.x * 4 + (threadIdx.x >> 6);
    if (d >= NN) return;
    const bool f = fl[0] != 0;
    const int hl = lane >> 4;
    const int start = rowptr[d], end = rowptr[d + 1];
    float m0 = -1e30f, m1 = -1e30f, m2 = -1e30f, m3 = -1e30f;
    float l0 = 0.f, l1 = 0.f, l2 = 0.f, l3 = 0.f;
    float acc0 = 0.f, acc1 = 0.f;
    for (int c0 = start; c0 < end; c0 += 64) {
        int n = end - c0;
        if (n > 64) n = 64;
        float a0, a1, a2, a3;
        int sr = 0;
        if (lane < n) {
            int e = elist[c0 + lane];
            int src = ei[e], r = et[e];
            sr = src * RR + r;
            float4 si = *(const float4*)&sb[(size_t)(d * RR + r) * 4];
            float4 tj = *(const float4*)&tb[(size_t)sr * 4];
            a0 = si.x + tj.x; a0 = a0 >= 0.f ? a0 : 0.2f * a0;
            a1 = si.y + tj.y; a1 = a1 >= 0.f ? a1 : 0.2f * a1;
            a2 = si.z + tj.z; a2 = a2 >= 0.f ? a2 : 0.2f * a2;
            a3 = si.w + tj.w; a3 = a3 >= 0.f ? a3 : 0.2f * a3;
        } else { a0 = a1 = a2 = a3 = -1e30f; }
        float n0 = fmaxf(m0, wredmax(a0));
        float n1 = fmaxf(m1, wredmax(a1));
        float n2 = fmaxf(m2, wredmax(a2));
        float n3 = fmaxf(m3, wredmax(a3));
        float s0 = __expf(m0 - n0), s1 = __expf(m1 - n1);
        float s2 = __expf(m2 - n2), s3 = __expf(m3 - n3);
        float e0 = __expf(a0 - n0), e1 = __expf(a1 - n1);
        float e2 = __expf(a2 - n2), e3 = __expf(a3 - n3);
        l0 = l0 * s0 + wredsum(e0);
        l1 = l1 * s1 + wredsum(e1);
        l2 = l2 * s2 + wredsum(e2);
        l3 = l3 * s3 + wredsum(e3);
        float scl = hl == 0 ? s0 : hl == 1 ? s1 : hl == 2 ? s2 : s3;
        acc0 *= scl; acc1 *= scl;
        for (int j = 0; j < n; j++) {
            int srj = __shfl(sr, j);
            float wx = __shfl(e0, j), wy = __shfl(e1, j);
            float wz = __shfl(e2, j), ww = __shfl(e3, j);
            float wgt = hl == 0 ? wx : hl == 1 ? wy : hl == 2 ? wz : ww;
            ushort2 uv = *(const ushort2*)((const u16*)xw + (size_t)srj * HIDC + lane * 2);
            acc0 += wgt * us2f(uv.x);
            acc1 += wgt * us2f(uv.y);
        }
        m0 = n0; m1 = n1; m2 = n2; m3 = n3;
    }
    float ld = hl == 0 ? l0 : hl == 1 ? l1 : hl == 2 ? l2 : l3;
    float inv = 1.f / (ld + 1e-16f);
    float v0 = acc0 * inv + ldf(b, 2 * lane, f);
    float v1 = acc1 * inv + ldf(b, 2 * lane + 1, f);
    v0 = fmaxf(v0, 0.f);
    v1 = fmaxf(v1, 0.f);
    float mean = wredsum(v0 + v1) * (1.f / 128.f);
    float d0 = v0 - mean, d1 = v1 - mean;
    float rstd = rsqrtf(wredsum(d0 * d0 + d1 * d1) * (1.f / 128.f) + 1e-5f);
    float y0 = d0 * rstd * ldf(g, 2 * lane, f) + ldf(bb, 2 * lane, f);
    float y1 = d1 * rstd * ldf(g, 2 * lane + 1, f) + ldf(bb, 2 * lane + 1, f);
    if (hprev) {
        y0 += hprev[(size_t)d * HIDC + 2 * lane];
        y1 += hprev[(size_t)d * HIDC + 2 * lane + 1];
    }
    *(float2*)&hout[(size_t)d * HIDC + 2 * lane] = float2{y0, y1};
}

// ---------------- mw1 + mw2 -> B-fragment order (bf16) for MFMA decode ----------------
// idx 0..4095: mw1 frags (8 col-tiles x 8 k-chunks). idx 4096..4351: mw2 frags
// (1 col-tile [8 valid cols + 8 zero] x 4 k-chunks).
__global__ void k_dswz(const void* __restrict__ mw1, const void* __restrict__ mw2,
                       u16* __restrict__ Wf, const int* __restrict__ fl) {
    int idx = blockIdx.x * 256 + threadIdx.x;  // 0..4351
    if (idx >= 4352) return;
    const bool f = fl[0] != 0;
    u16 o[8];
    if (idx < 4096) {
        int c = idx >> 9, q = (idx >> 6) & 7, ln = idx & 63;
        int k0 = q * 32 + (ln >> 4) * 8;
        int nn = c * 16 + (ln & 15);
#pragma unroll
        for (int j = 0; j < 8; j++)
            o[j] = f2us(ldf(mw1, (k0 + j) * HIDC + nn, f));
    } else {
        int fidx = idx - 4096;           // q*64 + lane
        int q = fidx >> 6, ln = fidx & 63;
        int k0 = q * 32 + (ln >> 4) * 8;
        int nn = ln & 15;
#pragma unroll
        for (int j = 0; j < 8; j++)
            o[j] = (nn < 8) ? f2us(ldf(mw2, (k0 + j) * NCL + nn, f)) : (u16)0;
    }
    *(ushort4*)&Wf[idx * 8]     = ushort4{o[0], o[1], o[2], o[3]};
    *(ushort4*)&Wf[idx * 8 + 4] = ushort4{o[4], o[5], o[6], o[7]};
}

// ---------------- decode (both GEMMs in MFMA) ----------------
// stage concat(h[a],h[b]) bf16 -> MFMA1 (K=256) -> +mb1, GELU -> bf16 LDS (A-layout)
// -> MFMA2 vs mw2 frags (K=128, N=16 w/ 8 zero-pad) -> +mb2 -> store
__global__ __launch_bounds__(256) void k_decode2(const float* __restrict__ h,
                                                 const int* __restrict__ edges,
                                                 const u16* __restrict__ Wf,
                                                 const void* __restrict__ mb1,
                                                 const void* __restrict__ mb2,
                                                 void* __restrict__ out,
                                                 const int* __restrict__ fl) {
    __shared__ u16 AshU[64 * 264];   // 33.8 KB; reused as zsu [64][136] u16 after af loaded
    __shared__ float mb2s[NCL];
    const int tid = threadIdx.x;
    const bool f = fl[0] != 0;
    const int p0 = blockIdx.x * 64;
    if (tid < NCL) mb2s[tid] = ldf(mb2, tid, f);
    for (int v = tid; v < 4096; v += 256) {
        int p = v >> 6, ch = v & 63;
        int half = ch >> 5, cc = (ch & 31) * 4;
        int node = edges[(size_t)(p0 + p) * 2 + half];
        float4 hv = *(const float4*)&h[(size_t)node * HIDC + cc];
        ushort4 o = {f2us(hv.x), f2us(hv.y), f2us(hv.z), f2us(hv.w)};
        *(ushort4*)&AshU[p * 264 + half * HIDC + cc] = o;
    }
    __syncthreads();
    const int w = tid >> 6, lane = tid & 63;
    short8 af[8];
#pragma unroll
    for (int q = 0; q < 8; q++)
        af[q] = *(const short8*)&AshU[(16 * w + (lane & 15)) * 264 + q * 32 + (lane >> 4) * 8];
    __syncthreads();  // all waves hold af; AshU reusable as zsu (wave-local rows)
    u16* zsu = AshU;  // [64][136] bf16
#pragma unroll
    for (int c = 0; c < 8; c++) {
        floatx4 acc = {0.f, 0.f, 0.f, 0.f};
#pragma unroll
        for (int q = 0; q < 8; q++) {
            short8 bfr = *(const short8*)&Wf[(size_t)(((c * 8 + q) * 64 + lane) * 8)];
            acc = __builtin_amdgcn_mfma_f32_16x16x32_bf16(af[q], bfr, acc, 0, 0, 0);
        }
        int col = c * 16 + (lane & 15);
        float bv = ldf(mb1, col, f);
#pragma unroll
        for (int reg = 0; reg < 4; reg++) {
            int p = 16 * w + (lane >> 4) * 4 + reg;
            float z = acc[reg] + bv;
            zsu[p * 136 + col] = f2us(0.5f * z * (1.f + erff(z * 0.70710678118654752f)));
        }
    }
    // second GEMM: rows are wave-local (16w..16w+15) — no block sync needed
    floatx4 acc2 = {0.f, 0.f, 0.f, 0.f};
#pragma unroll
    for (int q = 0; q < 4; q++) {
        short8 af2 = *(const short8*)&zsu[(16 * w + (lane & 15)) * 136 + q * 32 + (lane >> 4) * 8];
        short8 bfr2 = *(const short8*)&Wf[32768 + (size_t)((q * 64 + lane) * 8)];
        acc2 = __builtin_amdgcn_mfma_f32_16x16x32_bf16(af2, bfr2, acc2, 0, 0, 0);
    }
    int col16 = lane & 15;
    if (col16 < 8) {
        float bv2 = mb2s[col16];
#pragma unroll
        for (int reg = 0; reg < 4; reg++) {
            int p = 16 * w + (lane >> 4) * 4 + reg;
            float sv = acc2[reg] + bv2;
            size_t oi = (size_t)(p0 + p) * NCL + col16;
            if (f) ((float*)out)[oi] = sv;
            else   ((bf16*)out)[oi] = __float2bfloat16(sv);
        }
    }
}

extern "C" void kernel_launch(void* const* d_in, const int* in_sizes, int n_in,
                              void* d_out, int out_size, void* d_ws, size_t ws_size,
                              hipStream_t stream) {
    (void)in_sizes; (void)n_in; (void)out_size; (void)ws_size;
    const void* x    = d_in[0];
    const int* ei    = (const int*)d_in[1];
    const int* et    = (const int*)d_in[2];
    const int* edges = (const int*)d_in[3];
    const void* w1 = d_in[4];
    const void* q1 = d_in[5];
    const void* k1 = d_in[6];
    const void* b1 = d_in[7];
    const void* w2 = d_in[8];
    const void* q2 = d_in[9];
    const void* k2 = d_in[10];
    const void* b2 = d_in[11];
    const void* ln1g = d_in[12];
    const void* ln1b = d_in[13];
    const void* ln2g = d_in[14];
    const void* ln2b = d_in[15];
    const void* mw1 = d_in[16];
    const void* mb1 = d_in[17];
    const void* mw2 = d_in[18];
    const void* mb2 = d_in[19];

    // workspace layout — within round-3-proven bound (<= 169,425,560 B)
    char* ws = (char*)d_ws;
    bf16* xwb   = (bf16*)ws;                      // [0, 102,400,000)
    u16* Wf     = (u16*)ws;                       // ALIAS xwb: k_dswz runs after last xwb read (69,632 B)
    float* sbuf = (float*)(ws + 102400000);       // 6.4 MB
    float* tbuf = (float*)(ws + 108800000);       // 6.4 MB
    float* h1   = (float*)(ws + 115200000);       // 25.6 MB
    float* hsum = (float*)(ws + 140800000);       // 25.6 MB
    u16* Wf2    = (u16*)(ws + 140800000);         // ALIAS hsum: dead before hsum is written (589,824 B)
    int* rowptr = (int*)(ws + 166400000);         // NN+1 ints
    int* cursor = (int*)(ws + 166600016);         // NN ints
    int* elist  = (int*)(ws + 166800016);         // EE ints
    float* qkw  = (float*)(ws + 169360016);       // 65,536 B -> ends 169,425,552
    int* flags  = (int*)(ws + 169425552);         // 8 B -> ends 169,425,560 (proven)

    k_sniff<<<1, 1024, 0, stream>>>((const u16*)x, flags);

    // CSR build + weight preprocessing
    k_zero<<<196, 256, 0, stream>>>(cursor, NN);
    k_hist<<<2500, 256, 0, stream>>>(ei, cursor);
    k_scan<<<1, 1024, 0, stream>>>(cursor, rowptr);
    k_scatter<<<2500, 256, 0, stream>>>(ei, cursor, elist);
    k_qkw<<<64, 256, 0, stream>>>(w1, w2, q1, k1, q2, k2, qkw, flags);
    k_wswz<<<144, 256, 0, stream>>>(w1, w2, qkw, Wf2, flags);

    for (int layer = 0; layer < 2; ++layer) {
        const void* b  = layer ? b2 : b1;
        const void* lg = layer ? ln2g : ln1g;
        const void* lb = layer ? ln2b : ln1b;
        k_xw2<<<dim3(782, 8), 256, 0, stream>>>(layer ? (const void*)h1 : x, Wf2, xwb,
                                                sbuf, tbuf,
                                                layer ? flags + 1 : flags, layer);
        k_attn<<<12500, 256, 0, stream>>>(rowptr, elist, ei, et, sbuf, tbuf, xwb,
                                          b, lg, lb,
                                          layer ? h1 : (const float*)nullptr,
                                          layer ? hsum : h1, flags);
    }
    // decode weight swizzle into xwb space (xwb dead after attn L1)
    k_dswz<<<17, 256, 0, stream>>>(mw1, mw2, Wf, flags);
    k_decode2<<<3125, 256, 0, stream>>>(hsum, edges, Wf, mb1, mb2, d_out, flags);
}

// Round 10
// 586.225 us; speedup vs baseline: 5.7866x; 1.1713x over previous
//
#include <hip/hip_runtime.h>
#include <hip/hip_bf16.h>

#define NN    50000
#define RR    8
#define HIDC  128
#define NHEADS 4
#define EE    640000
#define EE2   200000
#define NCL   8

typedef __hip_bfloat16 bf16;
typedef unsigned short u16;
typedef __attribute__((ext_vector_type(8))) short short8;
typedef __attribute__((ext_vector_type(4))) float floatx4;

__device__ __forceinline__ float us2f(u16 u) {
    return __uint_as_float(((unsigned)u) << 16);
}
__device__ __forceinline__ float bf2f(bf16 v) { return __bfloat162float(v); }
__device__ __forceinline__ u16 f2us(float f) {
    bf16 h = __float2bfloat16(f);
    return *(u16*)&h;
}
__device__ __forceinline__ float ldf(const void* p, int i, bool f32) {
    return f32 ? ((const float*)p)[i] : us2f(((const u16*)p)[i]);
}
__device__ __forceinline__ float wredmax(float v) {
#pragma unroll
    for (int off = 32; off; off >>= 1) v = fmaxf(v, __shfl_xor(v, off));
    return v;
}
__device__ __forceinline__ float wredsum(float v) {
#pragma unroll
    for (int off = 32; off; off >>= 1) v += __shfl_xor(v, off);
    return v;
}

// ---------------- dtype sniff: fp32 data viewed as bf16 has exp==0xFF hits ----------------
__global__ __launch_bounds__(1024) void k_sniff(const u16* __restrict__ x, int* __restrict__ flags) {
    __shared__ int cnt;
    if (threadIdx.x == 0) cnt = 0;
    __syncthreads();
    int c = 0;
#pragma unroll
    for (int it = 0; it < 8; it++) {
        ushort4 a = ((const ushort4*)x)[(it * 1024 + threadIdx.x) * 2];
        ushort4 b = ((const ushort4*)x)[(it * 1024 + threadIdx.x) * 2 + 1];
        c += (((a.x >> 7) & 0xFF) == 0xFF) + (((a.y >> 7) & 0xFF) == 0xFF)
           + (((a.z >> 7) & 0xFF) == 0xFF) + (((a.w >> 7) & 0xFF) == 0xFF)
           + (((b.x >> 7) & 0xFF) == 0xFF) + (((b.y >> 7) & 0xFF) == 0xFF)
           + (((b.z >> 7) & 0xFF) == 0xFF) + (((b.w >> 7) & 0xFF) == 0xFF);
    }
    c += __shfl_xor(c, 32); c += __shfl_xor(c, 16); c += __shfl_xor(c, 8);
    c += __shfl_xor(c, 4);  c += __shfl_xor(c, 2);  c += __shfl_xor(c, 1);
    if ((threadIdx.x & 63) == 0) atomicAdd(&cnt, c);
    __syncthreads();
    if (threadIdx.x == 0) { flags[0] = (cnt > 16) ? 1 : 0; flags[1] = 1; }
}

// ---------------- CSR build ----------------
__global__ void k_zero(int* __restrict__ p, int n) {
    int i = blockIdx.x * 256 + threadIdx.x;
    if (i < n) p[i] = 0;
}
__global__ void k_hist(const int* __restrict__ ei, int* __restrict__ deg) {
    int e = blockIdx.x * 256 + threadIdx.x;
    if (e < EE) atomicAdd(&deg[ei[EE + e]], 1);
}
// 3-phase parallel scan: (1) per-block sums, (2) scan block sums, (3) per-block scan+base
__global__ __launch_bounds__(256) void k_scan1(const int* __restrict__ deg,
                                               int* __restrict__ bsum) {
    int i = blockIdx.x * 256 + threadIdx.x;
    int v = (i < NN) ? deg[i] : 0;
    __shared__ int red[4];
    int lane = threadIdx.x & 63, w = threadIdx.x >> 6;
#pragma unroll
    for (int off = 32; off; off >>= 1) v += __shfl_xor(v, off);
    if (lane == 0) red[w] = v;
    __syncthreads();
    if (threadIdx.x == 0) bsum[blockIdx.x] = red[0] + red[1] + red[2] + red[3];
}
__global__ __launch_bounds__(256) void k_scan2(const int* __restrict__ bsum,
                                               int* __restrict__ boff,
                                               int* __restrict__ rowptr) {
    __shared__ int s[256];
    int t = threadIdx.x;
    s[t] = (t < 196) ? bsum[t] : 0;
    __syncthreads();
    for (int off = 1; off < 256; off <<= 1) {
        int u = (t >= off) ? s[t - off] : 0;
        __syncthreads();
        s[t] += u;
        __syncthreads();
    }
    if (t < 196) boff[t] = (t == 0) ? 0 : s[t - 1];
    if (t == 255) rowptr[NN] = s[255];
}
__global__ __launch_bounds__(256) void k_scan3(int* __restrict__ deg /*in deg, out cursor*/,
                                               const int* __restrict__ boff,
                                               int* __restrict__ rowptr) {
    __shared__ int s[256];
    int t = threadIdx.x;
    int i = blockIdx.x * 256 + t;
    int v = (i < NN) ? deg[i] : 0;
    s[t] = v;
    __syncthreads();
    for (int off = 1; off < 256; off <<= 1) {
        int u = (t >= off) ? s[t - off] : 0;
        __syncthreads();
        s[t] += u;
        __syncthreads();
    }
    if (i < NN) {
        int val = boff[blockIdx.x] + s[t] - v;  // exclusive
        rowptr[i] = val;
        deg[i] = val;  // cursor copy
    }
}
__global__ void k_scatter(const int* __restrict__ ei, int* __restrict__ cursor,
                          int* __restrict__ elist) {
    int e = blockIdx.x * 256 + threadIdx.x;
    if (e >= EE) return;
    int pos = atomicAdd(&cursor[ei[EE + e]], 1);
    elist[pos] = e;
}

// ---------------- qkw[mat][i][h8] = sum_o W[r][i][o] * (q|k)[o][h] ----------------
__global__ void k_qkw(const void* __restrict__ w1, const void* __restrict__ w2,
                      const void* __restrict__ q1, const void* __restrict__ k1,
                      const void* __restrict__ q2, const void* __restrict__ k2,
                      float* __restrict__ qkw, const int* __restrict__ fl) {
    int idx = blockIdx.x * 256 + threadIdx.x;  // 16*128*8 = 16384
    if (idx >= 16384) return;
    const bool f = fl[0] != 0;
    int mat = idx >> 10;
    int i   = (idx >> 3) & 127;
    int h8  = idx & 7;
    const void* W = (mat >= 8) ? w2 : w1;
    const void* qk = (mat >= 8) ? ((h8 < 4) ? q2 : k2) : ((h8 < 4) ? q1 : k1);
    int h = h8 & 3;
    int r = mat & 7;
    float acc = 0.f;
    for (int o = 0; o < HIDC; o++)
        acc += ldf(W, (r * HIDC + i) * HIDC + o, f) * ldf(qk, o * NHEADS + h, f);
    qkw[idx] = acc;
}

// ---------------- W (+qkw cols) -> MFMA B-fragment order: 9 col-tiles ----------------
__global__ void k_wswz(const void* __restrict__ w1, const void* __restrict__ w2,
                       const float* __restrict__ qkw,
                       u16* __restrict__ Wf2, const int* __restrict__ fl) {
    int idx = blockIdx.x * 256 + threadIdx.x;  // 16 * 2304 = 36864
    if (idx >= 36864) return;
    const bool f = fl[0] != 0;
    int mat = idx / 2304, rest = idx % 2304;
    int c = rest >> 8, q = (rest >> 6) & 3, ln = rest & 63;
    int k0 = q * 32 + (ln >> 4) * 8;
    int nn = c * 16 + (ln & 15);
    int r = mat & 7;
    u16 o[8];
    if (c < 8) {
        const void* W = (mat >= 8) ? w2 : w1;
#pragma unroll
        for (int j = 0; j < 8; j++)
            o[j] = f2us(ldf(W, (r * HIDC + k0 + j) * HIDC + nn, f));
    } else {
        int col = nn - 128;  // 0..15
#pragma unroll
        for (int j = 0; j < 8; j++)
            o[j] = (col < 8) ? f2us(qkw[mat * 1024 + (k0 + j) * 8 + col]) : (u16)0;
    }
    u16* dst = Wf2 + (size_t)mat * 18432 + (size_t)(((c * 4 + q) * 64 + ln) * 8);
    *(ushort4*)dst       = ushort4{o[0], o[1], o[2], o[3]};
    *(ushort4*)(dst + 4) = ushort4{o[4], o[5], o[6], o[7]};
}

// ---------------- MFMA xw + s/t from col-tile 8 ----------------
__global__ __launch_bounds__(256) void k_xw2(const void* __restrict__ X,
                                             const u16* __restrict__ Wf2,
                                             bf16* __restrict__ xw,
                                             float* __restrict__ sbuf,
                                             float* __restrict__ tbuf,
                                             const int* __restrict__ fx,
                                             int layer) {
    __shared__ u16 Xs[64 * 136];    // 17.4 KB bf16 input tile
    __shared__ float Os[64 * 132];  // 33.8 KB fp32 output tile
    const int tid = threadIdx.x;
    const int r = blockIdx.y;
    const int n0 = blockIdx.x * 64;
    const bool xf = fx[0] != 0;
    for (int v = tid; v < 2048; v += 256) {
        int row = v >> 5, c4 = (v & 31) * 4, n = n0 + row;
        ushort4 o = {0, 0, 0, 0};
        if (n < NN) {
            if (xf) {
                float4 hv = *(const float4*)((const float*)X + (size_t)n * HIDC + c4);
                o = ushort4{f2us(hv.x), f2us(hv.y), f2us(hv.z), f2us(hv.w)};
            } else {
                o = *(const ushort4*)((const u16*)X + (size_t)n * HIDC + c4);
            }
        }
        *(ushort4*)&Xs[row * 136 + c4] = o;
    }
    __syncthreads();
    const int w = tid >> 6, lane = tid & 63;
    short8 af[4];
#pragma unroll
    for (int q = 0; q < 4; q++)
        af[q] = *(const short8*)&Xs[(16 * w + (lane & 15)) * 136 + q * 32 + (lane >> 4) * 8];
    const u16* Wfr = Wf2 + (size_t)(layer * 8 + r) * 18432;
#pragma unroll
    for (int c = 0; c < 9; c++) {
        floatx4 acc = {0.f, 0.f, 0.f, 0.f};
#pragma unroll
        for (int q = 0; q < 4; q++) {
            short8 bfr = *(const short8*)&Wfr[(size_t)(((c * 4 + q) * 64 + lane) * 8)];
            acc = __builtin_amdgcn_mfma_f32_16x16x32_bf16(af[q], bfr, acc, 0, 0, 0);
        }
        if (c < 8) {
            int col = c * 16 + (lane & 15);
#pragma unroll
            for (int reg = 0; reg < 4; reg++) {
                int p = 16 * w + (lane >> 4) * 4 + reg;
                Os[p * 132 + col] = acc[reg];
            }
        } else {
            int cl = lane & 15;  // 0..3 -> s heads, 4..7 -> t heads
            if (cl < 8) {
                float* dstp = (cl < 4) ? sbuf : tbuf;
                int h = cl & 3;
#pragma unroll
                for (int reg = 0; reg < 4; reg++) {
                    int p = 16 * w + (lane >> 4) * 4 + reg;
                    int n = n0 + p;
                    if (n < NN) dstp[(size_t)(n * RR + r) * 4 + h] = acc[reg];
                }
            }
        }
    }
    __syncthreads();
    for (int v = tid; v < 2048; v += 256) {
        int row = v >> 5, c4 = (v & 31) * 4, n = n0 + row;
        if (n < NN) {
            float4 hv = *(const float4*)&Os[row * 132 + c4];
            ushort4 o = {f2us(hv.x), f2us(hv.y), f2us(hv.z), f2us(hv.w)};
            *(ushort4*)((u16*)xw + (size_t)(n * RR + r) * HIDC + c4) = o;
        }
    }
}

// ---------------- fused attention: softmax over CSR edges + aggregate + bias/ReLU/LN ----------------
__global__ __launch_bounds__(256) void k_attn(const int* __restrict__ rowptr,
                                              const int* __restrict__ elist,
                                              const int* __restrict__ ei,
                                              const int* __restrict__ et,
                                              const float* __restrict__ sb,
                                              const float* __restrict__ tb,
                                              const bf16* __restrict__ xw,
                                              const void* __restrict__ b,
                                              const void* __restrict__ g,
                                              const void* __restrict__ bb,
                                              const float* __restrict__ hprev,
                                              float* __restrict__ hout,
                                              const int* __restrict__ fl) {
    const int lane = threadIdx.x & 63;
    const int d = blockIdx.x * 4 + (threadIdx.x >> 6);
    if (d >= NN) return;
    const bool f = fl[0] != 0;
    const int hl = lane >> 4;
    const int start = rowptr[d], end = rowptr[d + 1];
    float m0 = -1e30f, m1 = -1e30f, m2 = -1e30f, m3 = -1e30f;
    float l0 = 0.f, l1 = 0.f, l2 = 0.f, l3 = 0.f;
    float acc0 = 0.f, acc1 = 0.f;
    for (int c0 = start; c0 < end; c0 += 64) {
        int n = end - c0;
        if (n > 64) n = 64;
        float a0, a1, a2, a3;
        int sr = 0;
        if (lane < n) {
            int e = elist[c0 + lane];
            int src = ei[e], r = et[e];
            sr = src * RR + r;
            float4 si = *(const float4*)&sb[(size_t)(d * RR + r) * 4];
            float4 tj = *(const float4*)&tb[(size_t)sr * 4];
            a0 = si.x + tj.x; a0 = a0 >= 0.f ? a0 : 0.2f * a0;
            a1 = si.y + tj.y; a1 = a1 >= 0.f ? a1 : 0.2f * a1;
            a2 = si.z + tj.z; a2 = a2 >= 0.f ? a2 : 0.2f * a2;
            a3 = si.w + tj.w; a3 = a3 >= 0.f ? a3 : 0.2f * a3;
        } else { a0 = a1 = a2 = a3 = -1e30f; }
        float n0 = fmaxf(m0, wredmax(a0));
        float n1 = fmaxf(m1, wredmax(a1));
        float n2 = fmaxf(m2, wredmax(a2));
        float n3 = fmaxf(m3, wredmax(a3));
        float s0 = __expf(m0 - n0), s1 = __expf(m1 - n1);
        float s2 = __expf(m2 - n2), s3 = __expf(m3 - n3);
        float e0 = __expf(a0 - n0), e1 = __expf(a1 - n1);
        float e2 = __expf(a2 - n2), e3 = __expf(a3 - n3);
        l0 = l0 * s0 + wredsum(e0);
        l1 = l1 * s1 + wredsum(e1);
        l2 = l2 * s2 + wredsum(e2);
        l3 = l3 * s3 + wredsum(e3);
        float scl = hl == 0 ? s0 : hl == 1 ? s1 : hl == 2 ? s2 : s3;
        acc0 *= scl; acc1 *= scl;
        for (int j = 0; j < n; j++) {
            int srj = __shfl(sr, j);
            float wx = __shfl(e0, j), wy = __shfl(e1, j);
            float wz = __shfl(e2, j), ww = __shfl(e3, j);
            float wgt = hl == 0 ? wx : hl == 1 ? wy : hl == 2 ? wz : ww;
            ushort2 uv = *(const ushort2*)((const u16*)xw + (size_t)srj * HIDC + lane * 2);
            acc0 += wgt * us2f(uv.x);
            acc1 += wgt * us2f(uv.y);
        }
        m0 = n0; m1 = n1; m2 = n2; m3 = n3;
    }
    float ld = hl == 0 ? l0 : hl == 1 ? l1 : hl == 2 ? l2 : l3;
    float inv = 1.f / (ld + 1e-16f);
    float v0 = acc0 * inv + ldf(b, 2 * lane, f);
    float v1 = acc1 * inv + ldf(b, 2 * lane + 1, f);
    v0 = fmaxf(v0, 0.f);
    v1 = fmaxf(v1, 0.f);
    float mean = wredsum(v0 + v1) * (1.f / 128.f);
    float d0 = v0 - mean, d1 = v1 - mean;
    float rstd = rsqrtf(wredsum(d0 * d0 + d1 * d1) * (1.f / 128.f) + 1e-5f);
    float y0 = d0 * rstd * ldf(g, 2 * lane, f) + ldf(bb, 2 * lane, f);
    float y1 = d1 * rstd * ldf(g, 2 * lane + 1, f) + ldf(bb, 2 * lane + 1, f);
    if (hprev) {
        y0 += hprev[(size_t)d * HIDC + 2 * lane];
        y1 += hprev[(size_t)d * HIDC + 2 * lane + 1];
    }
    *(float2*)&hout[(size_t)d * HIDC + 2 * lane] = float2{y0, y1};
}

// ---------------- mw1 + mw2 -> B-fragment order (bf16) for MFMA decode ----------------
__global__ void k_dswz(const void* __restrict__ mw1, const void* __restrict__ mw2,
                       u16* __restrict__ Wf, const int* __restrict__ fl) {
    int idx = blockIdx.x * 256 + threadIdx.x;  // 0..4351
    if (idx >= 4352) return;
    const bool f = fl[0] != 0;
    u16 o[8];
    if (idx < 4096) {
        int c = idx >> 9, q = (idx >> 6) & 7, ln = idx & 63;
        int k0 = q * 32 + (ln >> 4) * 8;
        int nn = c * 16 + (ln & 15);
#pragma unroll
        for (int j = 0; j < 8; j++)
            o[j] = f2us(ldf(mw1, (k0 + j) * HIDC + nn, f));
    } else {
        int fidx = idx - 4096;           // q*64 + lane
        int q = fidx >> 6, ln = fidx & 63;
        int k0 = q * 32 + (ln >> 4) * 8;
        int nn = ln & 15;
#pragma unroll
        for (int j = 0; j < 8; j++)
            o[j] = (nn < 8) ? f2us(ldf(mw2, (k0 + j) * NCL + nn, f)) : (u16)0;
    }
    *(ushort4*)&Wf[idx * 8]     = ushort4{o[0], o[1], o[2], o[3]};
    *(ushort4*)&Wf[idx * 8 + 4] = ushort4{o[4], o[5], o[6], o[7]};
}

// ---------------- decode (both GEMMs in MFMA) ----------------
__global__ __launch_bounds__(256) void k_decode2(const float* __restrict__ h,
                                                 const int* __restrict__ edges,
                                                 const u16* __restrict__ Wf,
                                                 const void* __restrict__ mb1,
                                                 const void* __restrict__ mb2,
                                                 void* __restrict__ out,
                                                 const int* __restrict__ fl) {
    __shared__ u16 AshU[64 * 264];   // 33.8 KB; reused as zsu [64][136] u16 after af loaded
    __shared__ float mb2s[NCL];
    const int tid = threadIdx.x;
    const bool f = fl[0] != 0;
    const int p0 = blockIdx.x * 64;
    if (tid < NCL) mb2s[tid] = ldf(mb2, tid, f);
    for (int v = tid; v < 4096; v += 256) {
        int p = v >> 6, ch = v & 63;
        int half = ch >> 5, cc = (ch & 31) * 4;
        int node = edges[(size_t)(p0 + p) * 2 + half];
        float4 hv = *(const float4*)&h[(size_t)node * HIDC + cc];
        ushort4 o = {f2us(hv.x), f2us(hv.y), f2us(hv.z), f2us(hv.w)};
        *(ushort4*)&AshU[p * 264 + half * HIDC + cc] = o;
    }
    __syncthreads();
    const int w = tid >> 6, lane = tid & 63;
    short8 af[8];
#pragma unroll
    for (int q = 0; q < 8; q++)
        af[q] = *(const short8*)&AshU[(16 * w + (lane & 15)) * 264 + q * 32 + (lane >> 4) * 8];
    __syncthreads();  // all waves hold af; AshU reusable as zsu (wave-local rows)
    u16* zsu = AshU;  // [64][136] bf16
#pragma unroll
    for (int c = 0; c < 8; c++) {
        floatx4 acc = {0.f, 0.f, 0.f, 0.f};
#pragma unroll
        for (int q = 0; q < 8; q++) {
            short8 bfr = *(const short8*)&Wf[(size_t)(((c * 8 + q) * 64 + lane) * 8)];
            acc = __builtin_amdgcn_mfma_f32_16x16x32_bf16(af[q], bfr, acc, 0, 0, 0);
        }
        int col = c * 16 + (lane & 15);
        float bv = ldf(mb1, col, f);
#pragma unroll
        for (int reg = 0; reg < 4; reg++) {
            int p = 16 * w + (lane >> 4) * 4 + reg;
            float z = acc[reg] + bv;
            zsu[p * 136 + col] = f2us(0.5f * z * (1.f + erff(z * 0.70710678118654752f)));
        }
    }
    // second GEMM: rows are wave-local (16w..16w+15) — no block sync needed
    floatx4 acc2 = {0.f, 0.f, 0.f, 0.f};
#pragma unroll
    for (int q = 0; q < 4; q++) {
        short8 af2 = *(const short8*)&zsu[(16 * w + (lane & 15)) * 136 + q * 32 + (lane >> 4) * 8];
        short8 bfr2 = *(const short8*)&Wf[32768 + (size_t)((q * 64 + lane) * 8)];
        acc2 = __builtin_amdgcn_mfma_f32_16x16x32_bf16(af2, bfr2, acc2, 0, 0, 0);
    }
    int col16 = lane & 15;
    if (col16 < 8) {
        float bv2 = mb2s[col16];
#pragma unroll
        for (int reg = 0; reg < 4; reg++) {
            int p = 16 * w + (lane >> 4) * 4 + reg;
            float sv = acc2[reg] + bv2;
            size_t oi = (size_t)(p0 + p) * NCL + col16;
            if (f) ((float*)out)[oi] = sv;
            else   ((bf16*)out)[oi] = __float2bfloat16(sv);
        }
    }
}

extern "C" void kernel_launch(void* const* d_in, const int* in_sizes, int n_in,
                              void* d_out, int out_size, void* d_ws, size_t ws_size,
                              hipStream_t stream) {
    (void)in_sizes; (void)n_in; (void)out_size; (void)ws_size;
    const void* x    = d_in[0];
    const int* ei    = (const int*)d_in[1];
    const int* et    = (const int*)d_in[2];
    const int* edges = (const int*)d_in[3];
    const void* w1 = d_in[4];
    const void* q1 = d_in[5];
    const void* k1 = d_in[6];
    const void* b1 = d_in[7];
    const void* w2 = d_in[8];
    const void* q2 = d_in[9];
    const void* k2 = d_in[10];
    const void* b2 = d_in[11];
    const void* ln1g = d_in[12];
    const void* ln1b = d_in[13];
    const void* ln2g = d_in[14];
    const void* ln2b = d_in[15];
    const void* mw1 = d_in[16];
    const void* mb1 = d_in[17];
    const void* mw2 = d_in[18];
    const void* mb2 = d_in[19];

    // workspace layout — within round-3-proven bound (<= 169,425,560 B)
    char* ws = (char*)d_ws;
    bf16* xwb   = (bf16*)ws;                      // [0, 102,400,000)
    u16* Wf     = (u16*)ws;                       // ALIAS xwb: k_dswz runs after last xwb read (69,632 B)
    float* sbuf = (float*)(ws + 102400000);       // 6.4 MB
    float* tbuf = (float*)(ws + 108800000);       // 6.4 MB
    float* h1   = (float*)(ws + 115200000);       // 25.6 MB
    float* hsum = (float*)(ws + 140800000);       // 25.6 MB
    u16* Wf2    = (u16*)(ws + 140800000);         // ALIAS hsum: dead before hsum is written (589,824 B)
    int* rowptr = (int*)(ws + 166400000);         // NN+1 ints
    int* cursor = (int*)(ws + 166600016);         // NN ints
    int* elist  = (int*)(ws + 166800016);         // EE ints
    float* qkw  = (float*)(ws + 169360016);       // 65,536 B -> ends 169,425,552
    int* bsum   = (int*)qkw;                      // ALIAS qkw: scan phases finish before k_qkw writes
    int* boff   = bsum + 256;
    int* flags  = (int*)(ws + 169425552);         // 8 B -> ends 169,425,560 (proven)

    k_sniff<<<1, 1024, 0, stream>>>((const u16*)x, flags);

    // CSR build (parallel 3-phase scan) + weight preprocessing
    k_zero<<<196, 256, 0, stream>>>(cursor, NN);
    k_hist<<<2500, 256, 0, stream>>>(ei, cursor);
    k_scan1<<<196, 256, 0, stream>>>(cursor, bsum);
    k_scan2<<<1, 256, 0, stream>>>(bsum, boff, rowptr);
    k_scan3<<<196, 256, 0, stream>>>(cursor, boff, rowptr);
    k_scatter<<<2500, 256, 0, stream>>>(ei, cursor, elist);
    k_qkw<<<64, 256, 0, stream>>>(w1, w2, q1, k1, q2, k2, qkw, flags);
    k_wswz<<<144, 256, 0, stream>>>(w1, w2, qkw, Wf2, flags);

    for (int layer = 0; layer < 2; ++layer) {
        const void* b  = layer ? b2 : b1;
        const void* lg = layer ? ln2g : ln1g;
        const void* lb = layer ? ln2b : ln1b;
        k_xw2<<<dim3(782, 8), 256, 0, stream>>>(layer ? (const void*)h1 : x, Wf2, xwb,
                                                sbuf, tbuf,
                                                layer ? flags + 1 : flags, layer);
        k_attn<<<12500, 256, 0, stream>>>(rowptr, elist, ei, et, sbuf, tbuf, xwb,
                                          b, lg, lb,
                                          layer ? h1 : (const float*)nullptr,
                                          layer ? hsum : h1, flags);
    }
    // decode weight swizzle into xwb space (xwb dead after attn L1)
    k_dswz<<<17, 256, 0, stream>>>(mw1, mw2, Wf, flags);
    k_decode2<<<3125, 256, 0, stream>>>(hsum, edges, Wf, mb1, mb2, d_out, flags);
}

// Round 11
// 558.790 us; speedup vs baseline: 6.0707x; 1.0491x over previous
//
#include <hip/hip_runtime.h>
#include <hip/hip_bf16.h>

#define NN    50000
#define RR    8
#define HIDC  128
#define NHEADS 4
#define EE    640000
#define EE2   200000
#define NCL   8

typedef __hip_bfloat16 bf16;
typedef unsigned short u16;
typedef __attribute__((ext_vector_type(8))) short short8;
typedef __attribute__((ext_vector_type(4))) float floatx4;

__device__ __forceinline__ float us2f(u16 u) {
    return __uint_as_float(((unsigned)u) << 16);
}
__device__ __forceinline__ float bf2f(bf16 v) { return __bfloat162float(v); }
__device__ __forceinline__ u16 f2us(float f) {
    bf16 h = __float2bfloat16(f);
    return *(u16*)&h;
}
__device__ __forceinline__ float ldf(const void* p, int i, bool f32) {
    return f32 ? ((const float*)p)[i] : us2f(((const u16*)p)[i]);
}
__device__ __forceinline__ float wredmax(float v) {
#pragma unroll
    for (int off = 32; off; off >>= 1) v = fmaxf(v, __shfl_xor(v, off));
    return v;
}
__device__ __forceinline__ float wredsum(float v) {
#pragma unroll
    for (int off = 32; off; off >>= 1) v += __shfl_xor(v, off);
    return v;
}

// ---------------- dtype sniff: fp32 data viewed as bf16 has exp==0xFF hits ----------------
__global__ __launch_bounds__(1024) void k_sniff(const u16* __restrict__ x, int* __restrict__ flags) {
    __shared__ int cnt;
    if (threadIdx.x == 0) cnt = 0;
    __syncthreads();
    int c = 0;
#pragma unroll
    for (int it = 0; it < 8; it++) {
        ushort4 a = ((const ushort4*)x)[(it * 1024 + threadIdx.x) * 2];
        ushort4 b = ((const ushort4*)x)[(it * 1024 + threadIdx.x) * 2 + 1];
        c += (((a.x >> 7) & 0xFF) == 0xFF) + (((a.y >> 7) & 0xFF) == 0xFF)
           + (((a.z >> 7) & 0xFF) == 0xFF) + (((a.w >> 7) & 0xFF) == 0xFF)
           + (((b.x >> 7) & 0xFF) == 0xFF) + (((b.y >> 7) & 0xFF) == 0xFF)
           + (((b.z >> 7) & 0xFF) == 0xFF) + (((b.w >> 7) & 0xFF) == 0xFF);
    }
    c += __shfl_xor(c, 32); c += __shfl_xor(c, 16); c += __shfl_xor(c, 8);
    c += __shfl_xor(c, 4);  c += __shfl_xor(c, 2);  c += __shfl_xor(c, 1);
    if ((threadIdx.x & 63) == 0) atomicAdd(&cnt, c);
    __syncthreads();
    if (threadIdx.x == 0) { flags[0] = (cnt > 16) ? 1 : 0; flags[1] = 1; }
}

// ---------------- CSR build ----------------
__global__ void k_zero(int* __restrict__ p, int n) {
    int i = blockIdx.x * 256 + threadIdx.x;
    if (i < n) p[i] = 0;
}
__global__ void k_hist(const int* __restrict__ ei, int* __restrict__ deg) {
    int e = blockIdx.x * 256 + threadIdx.x;
    if (e < EE) atomicAdd(&deg[ei[EE + e]], 1);
}
// 3-phase parallel scan
__global__ __launch_bounds__(256) void k_scan1(const int* __restrict__ deg,
                                               int* __restrict__ bsum) {
    int i = blockIdx.x * 256 + threadIdx.x;
    int v = (i < NN) ? deg[i] : 0;
    __shared__ int red[4];
    int lane = threadIdx.x & 63, w = threadIdx.x >> 6;
#pragma unroll
    for (int off = 32; off; off >>= 1) v += __shfl_xor(v, off);
    if (lane == 0) red[w] = v;
    __syncthreads();
    if (threadIdx.x == 0) bsum[blockIdx.x] = red[0] + red[1] + red[2] + red[3];
}
__global__ __launch_bounds__(256) void k_scan2(const int* __restrict__ bsum,
                                               int* __restrict__ boff,
                                               int* __restrict__ rowptr) {
    __shared__ int s[256];
    int t = threadIdx.x;
    s[t] = (t < 196) ? bsum[t] : 0;
    __syncthreads();
    for (int off = 1; off < 256; off <<= 1) {
        int u = (t >= off) ? s[t - off] : 0;
        __syncthreads();
        s[t] += u;
        __syncthreads();
    }
    if (t < 196) boff[t] = (t == 0) ? 0 : s[t - 1];
    if (t == 255) rowptr[NN] = s[255];
}
__global__ __launch_bounds__(256) void k_scan3(int* __restrict__ deg /*in deg, out cursor*/,
                                               const int* __restrict__ boff,
                                               int* __restrict__ rowptr) {
    __shared__ int s[256];
    int t = threadIdx.x;
    int i = blockIdx.x * 256 + t;
    int v = (i < NN) ? deg[i] : 0;
    s[t] = v;
    __syncthreads();
    for (int off = 1; off < 256; off <<= 1) {
        int u = (t >= off) ? s[t - off] : 0;
        __syncthreads();
        s[t] += u;
        __syncthreads();
    }
    if (i < NN) {
        int val = boff[blockIdx.x] + s[t] - v;  // exclusive
        rowptr[i] = val;
        deg[i] = val;  // cursor copy
    }
}
__global__ void k_scatter(const int* __restrict__ ei, int* __restrict__ cursor,
                          int* __restrict__ elist) {
    int e = blockIdx.x * 256 + threadIdx.x;
    if (e >= EE) return;
    int pos = atomicAdd(&cursor[ei[EE + e]], 1);
    elist[pos] = e;
}

// ---------------- qkw[mat][i][h8] = sum_o W[r][i][o] * (q|k)[o][h] ----------------
__global__ void k_qkw(const void* __restrict__ w1, const void* __restrict__ w2,
                      const void* __restrict__ q1, const void* __restrict__ k1,
                      const void* __restrict__ q2, const void* __restrict__ k2,
                      float* __restrict__ qkw, const int* __restrict__ fl) {
    int idx = blockIdx.x * 256 + threadIdx.x;  // 16*128*8 = 16384
    if (idx >= 16384) return;
    const bool f = fl[0] != 0;
    int mat = idx >> 10;
    int i   = (idx >> 3) & 127;
    int h8  = idx & 7;
    const void* W = (mat >= 8) ? w2 : w1;
    const void* qk = (mat >= 8) ? ((h8 < 4) ? q2 : k2) : ((h8 < 4) ? q1 : k1);
    int h = h8 & 3;
    int r = mat & 7;
    float acc = 0.f;
    for (int o = 0; o < HIDC; o++)
        acc += ldf(W, (r * HIDC + i) * HIDC + o, f) * ldf(qk, o * NHEADS + h, f);
    qkw[idx] = acc;
}

// ---------------- W (+qkw cols) -> MFMA B-fragment order: 9 col-tiles ----------------
__global__ void k_wswz(const void* __restrict__ w1, const void* __restrict__ w2,
                       const float* __restrict__ qkw,
                       u16* __restrict__ Wf2, const int* __restrict__ fl) {
    int idx = blockIdx.x * 256 + threadIdx.x;  // 16 * 2304 = 36864
    if (idx >= 36864) return;
    const bool f = fl[0] != 0;
    int mat = idx / 2304, rest = idx % 2304;
    int c = rest >> 8, q = (rest >> 6) & 3, ln = rest & 63;
    int k0 = q * 32 + (ln >> 4) * 8;
    int nn = c * 16 + (ln & 15);
    int r = mat & 7;
    u16 o[8];
    if (c < 8) {
        const void* W = (mat >= 8) ? w2 : w1;
#pragma unroll
        for (int j = 0; j < 8; j++)
            o[j] = f2us(ldf(W, (r * HIDC + k0 + j) * HIDC + nn, f));
    } else {
        int col = nn - 128;  // 0..15
#pragma unroll
        for (int j = 0; j < 8; j++)
            o[j] = (col < 8) ? f2us(qkw[mat * 1024 + (k0 + j) * 8 + col]) : (u16)0;
    }
    u16* dst = Wf2 + (size_t)mat * 18432 + (size_t)(((c * 4 + q) * 64 + ln) * 8);
    *(ushort4*)dst       = ushort4{o[0], o[1], o[2], o[3]};
    *(ushort4*)(dst + 4) = ushort4{o[4], o[5], o[6], o[7]};
}

// ---------------- MFMA xw + s/t from col-tile 8 ----------------
__global__ __launch_bounds__(256) void k_xw2(const void* __restrict__ X,
                                             const u16* __restrict__ Wf2,
                                             bf16* __restrict__ xw,
                                             float* __restrict__ sbuf,
                                             float* __restrict__ tbuf,
                                             const int* __restrict__ fx,
                                             int layer) {
    __shared__ u16 Xs[64 * 136];    // 17.4 KB bf16 input tile
    __shared__ float Os[64 * 132];  // 33.8 KB fp32 output tile
    const int tid = threadIdx.x;
    const int r = blockIdx.y;
    const int n0 = blockIdx.x * 64;
    const bool xf = fx[0] != 0;
    for (int v = tid; v < 2048; v += 256) {
        int row = v >> 5, c4 = (v & 31) * 4, n = n0 + row;
        ushort4 o = {0, 0, 0, 0};
        if (n < NN) {
            if (xf) {
                float4 hv = *(const float4*)((const float*)X + (size_t)n * HIDC + c4);
                o = ushort4{f2us(hv.x), f2us(hv.y), f2us(hv.z), f2us(hv.w)};
            } else {
                o = *(const ushort4*)((const u16*)X + (size_t)n * HIDC + c4);
            }
        }
        *(ushort4*)&Xs[row * 136 + c4] = o;
    }
    __syncthreads();
    const int w = tid >> 6, lane = tid & 63;
    short8 af[4];
#pragma unroll
    for (int q = 0; q < 4; q++)
        af[q] = *(const short8*)&Xs[(16 * w + (lane & 15)) * 136 + q * 32 + (lane >> 4) * 8];
    const u16* Wfr = Wf2 + (size_t)(layer * 8 + r) * 18432;
#pragma unroll
    for (int c = 0; c < 9; c++) {
        floatx4 acc = {0.f, 0.f, 0.f, 0.f};
#pragma unroll
        for (int q = 0; q < 4; q++) {
            short8 bfr = *(const short8*)&Wfr[(size_t)(((c * 4 + q) * 64 + lane) * 8)];
            acc = __builtin_amdgcn_mfma_f32_16x16x32_bf16(af[q], bfr, acc, 0, 0, 0);
        }
        if (c < 8) {
            int col = c * 16 + (lane & 15);
#pragma unroll
            for (int reg = 0; reg < 4; reg++) {
                int p = 16 * w + (lane >> 4) * 4 + reg;
                Os[p * 132 + col] = acc[reg];
            }
        } else {
            int cl = lane & 15;  // 0..3 -> s heads, 4..7 -> t heads
            if (cl < 8) {
                float* dstp = (cl < 4) ? sbuf : tbuf;
                int h = cl & 3;
#pragma unroll
                for (int reg = 0; reg < 4; reg++) {
                    int p = 16 * w + (lane >> 4) * 4 + reg;
                    int n = n0 + p;
                    if (n < NN) dstp[(size_t)(n * RR + r) * 4 + h] = acc[reg];
                }
            }
        }
    }
    __syncthreads();
    for (int v = tid; v < 2048; v += 256) {
        int row = v >> 5, c4 = (v & 31) * 4, n = n0 + row;
        if (n < NN) {
            float4 hv = *(const float4*)&Os[row * 132 + c4];
            ushort4 o = {f2us(hv.x), f2us(hv.y), f2us(hv.z), f2us(hv.w)};
            *(ushort4*)((u16*)xw + (size_t)(n * RR + r) * HIDC + c4) = o;
        }
    }
}

// ---------------- fused attention: softmax over CSR edges + aggregate + bias/ReLU/LN ----------------
__global__ __launch_bounds__(256) void k_attn(const int* __restrict__ rowptr,
                                              const int* __restrict__ elist,
                                              const int* __restrict__ ei,
                                              const int* __restrict__ et,
                                              const float* __restrict__ sb,
                                              const float* __restrict__ tb,
                                              const bf16* __restrict__ xw,
                                              const void* __restrict__ b,
                                              const void* __restrict__ g,
                                              const void* __restrict__ bb,
                                              const float* __restrict__ hprev,
                                              float* __restrict__ hout,
                                              const int* __restrict__ fl) {
    const int lane = threadIdx.x & 63;
    const int d = blockIdx.x * 4 + (threadIdx.x >> 6);
    if (d >= NN) return;
    const bool f = fl[0] != 0;
    const int hl = lane >> 4;
    const int start = rowptr[d], end = rowptr[d + 1];
    float m0 = -1e30f, m1 = -1e30f, m2 = -1e30f, m3 = -1e30f;
    float l0 = 0.f, l1 = 0.f, l2 = 0.f, l3 = 0.f;
    float acc0 = 0.f, acc1 = 0.f;
    for (int c0 = start; c0 < end; c0 += 64) {
        int n = end - c0;
        if (n > 64) n = 64;
        float a0, a1, a2, a3;
        int sr = 0;
        if (lane < n) {
            int e = elist[c0 + lane];
            int src = ei[e], r = et[e];
            sr = src * RR + r;
            float4 si = *(const float4*)&sb[(size_t)(d * RR + r) * 4];
            float4 tj = *(const float4*)&tb[(size_t)sr * 4];
            a0 = si.x + tj.x; a0 = a0 >= 0.f ? a0 : 0.2f * a0;
            a1 = si.y + tj.y; a1 = a1 >= 0.f ? a1 : 0.2f * a1;
            a2 = si.z + tj.z; a2 = a2 >= 0.f ? a2 : 0.2f * a2;
            a3 = si.w + tj.w; a3 = a3 >= 0.f ? a3 : 0.2f * a3;
        } else { a0 = a1 = a2 = a3 = -1e30f; }
        float n0 = fmaxf(m0, wredmax(a0));
        float n1 = fmaxf(m1, wredmax(a1));
        float n2 = fmaxf(m2, wredmax(a2));
        float n3 = fmaxf(m3, wredmax(a3));
        float s0 = __expf(m0 - n0), s1 = __expf(m1 - n1);
        float s2 = __expf(m2 - n2), s3 = __expf(m3 - n3);
        float e0 = __expf(a0 - n0), e1 = __expf(a1 - n1);
        float e2 = __expf(a2 - n2), e3 = __expf(a3 - n3);
        l0 = l0 * s0 + wredsum(e0);
        l1 = l1 * s1 + wredsum(e1);
        l2 = l2 * s2 + wredsum(e2);
        l3 = l3 * s3 + wredsum(e3);
        float scl = hl == 0 ? s0 : hl == 1 ? s1 : hl == 2 ? s2 : s3;
        acc0 *= scl; acc1 *= scl;
        for (int j = 0; j < n; j++) {
            int srj = __shfl(sr, j);
            float wx = __shfl(e0, j), wy = __shfl(e1, j);
            float wz = __shfl(e2, j), ww = __shfl(e3, j);
            float wgt = hl == 0 ? wx : hl == 1 ? wy : hl == 2 ? wz : ww;
            ushort2 uv = *(const ushort2*)((const u16*)xw + (size_t)srj * HIDC + lane * 2);
            acc0 += wgt * us2f(uv.x);
            acc1 += wgt * us2f(uv.y);
        }
        m0 = n0; m1 = n1; m2 = n2; m3 = n3;
    }
    float ld = hl == 0 ? l0 : hl == 1 ? l1 : hl == 2 ? l2 : l3;
    float inv = 1.f / (ld + 1e-16f);
    float v0 = acc0 * inv + ldf(b, 2 * lane, f);
    float v1 = acc1 * inv + ldf(b, 2 * lane + 1, f);
    v0 = fmaxf(v0, 0.f);
    v1 = fmaxf(v1, 0.f);
    float mean = wredsum(v0 + v1) * (1.f / 128.f);
    float d0 = v0 - mean, d1 = v1 - mean;
    float rstd = rsqrtf(wredsum(d0 * d0 + d1 * d1) * (1.f / 128.f) + 1e-5f);
    float y0 = d0 * rstd * ldf(g, 2 * lane, f) + ldf(bb, 2 * lane, f);
    float y1 = d1 * rstd * ldf(g, 2 * lane + 1, f) + ldf(bb, 2 * lane + 1, f);
    if (hprev) {
        y0 += hprev[(size_t)d * HIDC + 2 * lane];
        y1 += hprev[(size_t)d * HIDC + 2 * lane + 1];
    }
    *(float2*)&hout[(size_t)d * HIDC + 2 * lane] = float2{y0, y1};
}

// ---------------- mw1 + mw2 -> B-fragment order (bf16) for MFMA decode ----------------
__global__ void k_dswz(const void* __restrict__ mw1, const void* __restrict__ mw2,
                       u16* __restrict__ Wf, const int* __restrict__ fl) {
    int idx = blockIdx.x * 256 + threadIdx.x;  // 0..4351
    if (idx >= 4352) return;
    const bool f = fl[0] != 0;
    u16 o[8];
    if (idx < 4096) {
        int c = idx >> 9, q = (idx >> 6) & 7, ln = idx & 63;
        int k0 = q * 32 + (ln >> 4) * 8;
        int nn = c * 16 + (ln & 15);
#pragma unroll
        for (int j = 0; j < 8; j++)
            o[j] = f2us(ldf(mw1, (k0 + j) * HIDC + nn, f));
    } else {
        int fidx = idx - 4096;           // q*64 + lane
        int q = fidx >> 6, ln = fidx & 63;
        int k0 = q * 32 + (ln >> 4) * 8;
        int nn = ln & 15;
#pragma unroll
        for (int j = 0; j < 8; j++)
            o[j] = (nn < 8) ? f2us(ldf(mw2, (k0 + j) * NCL + nn, f)) : (u16)0;
    }
    *(ushort4*)&Wf[idx * 8]     = ushort4{o[0], o[1], o[2], o[3]};
    *(ushort4*)&Wf[idx * 8 + 4] = ushort4{o[4], o[5], o[6], o[7]};
}

// ---------------- decode: barrier-free, direct global A-fragment gathers ----------------
// wave w owns rows 16w..16w+15; A-frag af[q][j] = concat(h[a],h[b])[m][q*32+g*8+j]
// loaded straight from global; GELU -> wave-local zsu LDS -> second MFMA -> store.
__global__ __launch_bounds__(256) void k_decode2(const float* __restrict__ h,
                                                 const int* __restrict__ edges,
                                                 const u16* __restrict__ Wf,
                                                 const void* __restrict__ mb1,
                                                 const void* __restrict__ mb2,
                                                 void* __restrict__ out,
                                                 const int* __restrict__ fl) {
    __shared__ u16 zsu[64 * 136];   // 17.4 KB, wave-local rows only
    const int tid = threadIdx.x;
    const bool f = fl[0] != 0;
    const int p0 = blockIdx.x * 64;
    const int w = tid >> 6, lane = tid & 63;
    const int m = 16 * w + (lane & 15);   // row in 64-tile
    const int g = lane >> 4;              // k-group 0..3
    const int na = edges[(size_t)(p0 + m) * 2];
    const int nb = edges[(size_t)(p0 + m) * 2 + 1];
    short8 af[8];
#pragma unroll
    for (int q = 0; q < 8; q++) {
        int k0 = q * 32 + g * 8;          // 0..248
        const float* src = h + (size_t)((k0 >> 7) ? nb : na) * HIDC + (k0 & 127);
        float4 a = *(const float4*)src;
        float4 bq = *(const float4*)(src + 4);
        u16 tmp[8] = {f2us(a.x), f2us(a.y), f2us(a.z), f2us(a.w),
                      f2us(bq.x), f2us(bq.y), f2us(bq.z), f2us(bq.w)};
        af[q] = *(short8*)tmp;
    }
#pragma unroll
    for (int c = 0; c < 8; c++) {
        floatx4 acc = {0.f, 0.f, 0.f, 0.f};
#pragma unroll
        for (int q = 0; q < 8; q++) {
            short8 bfr = *(const short8*)&Wf[(size_t)(((c * 8 + q) * 64 + lane) * 8)];
            acc = __builtin_amdgcn_mfma_f32_16x16x32_bf16(af[q], bfr, acc, 0, 0, 0);
        }
        int col = c * 16 + (lane & 15);
        float bv = ldf(mb1, col, f);
#pragma unroll
        for (int reg = 0; reg < 4; reg++) {
            int p = 16 * w + (lane >> 4) * 4 + reg;
            float z = acc[reg] + bv;
            zsu[p * 136 + col] = f2us(0.5f * z * (1.f + erff(z * 0.70710678118654752f)));
        }
    }
    // second GEMM: rows wave-local -> no barrier
    floatx4 acc2 = {0.f, 0.f, 0.f, 0.f};
#pragma unroll
    for (int q = 0; q < 4; q++) {
        short8 af2 = *(const short8*)&zsu[m * 136 + q * 32 + g * 8];
        short8 bfr2 = *(const short8*)&Wf[32768 + (size_t)((q * 64 + lane) * 8)];
        acc2 = __builtin_amdgcn_mfma_f32_16x16x32_bf16(af2, bfr2, acc2, 0, 0, 0);
    }
    int col16 = lane & 15;
    if (col16 < 8) {
        float bv2 = ldf(mb2, col16, f);
#pragma unroll
        for (int reg = 0; reg < 4; reg++) {
            int p = 16 * w + (lane >> 4) * 4 + reg;
            float sv = acc2[reg] + bv2;
            size_t oi = (size_t)(p0 + p) * NCL + col16;
            if (f) ((float*)out)[oi] = sv;
            else   ((bf16*)out)[oi] = __float2bfloat16(sv);
        }
    }
}

extern "C" void kernel_launch(void* const* d_in, const int* in_sizes, int n_in,
                              void* d_out, int out_size, void* d_ws, size_t ws_size,
                              hipStream_t stream) {
    (void)in_sizes; (void)n_in; (void)out_size; (void)ws_size;
    const void* x    = d_in[0];
    const int* ei    = (const int*)d_in[1];
    const int* et    = (const int*)d_in[2];
    const int* edges = (const int*)d_in[3];
    const void* w1 = d_in[4];
    const void* q1 = d_in[5];
    const void* k1 = d_in[6];
    const void* b1 = d_in[7];
    const void* w2 = d_in[8];
    const void* q2 = d_in[9];
    const void* k2 = d_in[10];
    const void* b2 = d_in[11];
    const void* ln1g = d_in[12];
    const void* ln1b = d_in[13];
    const void* ln2g = d_in[14];
    const void* ln2b = d_in[15];
    const void* mw1 = d_in[16];
    const void* mb1 = d_in[17];
    const void* mw2 = d_in[18];
    const void* mb2 = d_in[19];

    // workspace layout — within round-3-proven bound (<= 169,425,560 B)
    char* ws = (char*)d_ws;
    bf16* xwb   = (bf16*)ws;                      // [0, 102,400,000)
    u16* Wf     = (u16*)ws;                       // ALIAS xwb: k_dswz runs after last xwb read (69,632 B)
    float* sbuf = (float*)(ws + 102400000);       // 6.4 MB
    float* tbuf = (float*)(ws + 108800000);       // 6.4 MB
    float* h1   = (float*)(ws + 115200000);       // 25.6 MB
    float* hsum = (float*)(ws + 140800000);       // 25.6 MB
    u16* Wf2    = (u16*)(ws + 140800000);         // ALIAS hsum: dead before hsum is written (589,824 B)
    int* rowptr = (int*)(ws + 166400000);         // NN+1 ints
    int* cursor = (int*)(ws + 166600016);         // NN ints
    int* elist  = (int*)(ws + 166800016);         // EE ints
    float* qkw  = (float*)(ws + 169360016);       // 65,536 B -> ends 169,425,552
    int* bsum   = (int*)qkw;                      // ALIAS qkw: scan phases finish before k_qkw writes
    int* boff   = bsum + 256;
    int* flags  = (int*)(ws + 169425552);         // 8 B -> ends 169,425,560 (proven)

    k_sniff<<<1, 1024, 0, stream>>>((const u16*)x, flags);

    // CSR build (parallel 3-phase scan) + weight preprocessing
    k_zero<<<196, 256, 0, stream>>>(cursor, NN);
    k_hist<<<2500, 256, 0, stream>>>(ei, cursor);
    k_scan1<<<196, 256, 0, stream>>>(cursor, bsum);
    k_scan2<<<1, 256, 0, stream>>>(bsum, boff, rowptr);
    k_scan3<<<196, 256, 0, stream>>>(cursor, boff, rowptr);
    k_scatter<<<2500, 256, 0, stream>>>(ei, cursor, elist);
    k_qkw<<<64, 256, 0, stream>>>(w1, w2, q1, k1, q2, k2, qkw, flags);
    k_wswz<<<144, 256, 0, stream>>>(w1, w2, qkw, Wf2, flags);

    for (int layer = 0; layer < 2; ++layer) {
        const void* b  = layer ? b2 : b1;
        const void* lg = layer ? ln2g : ln1g;
        const void* lb = layer ? ln2b : ln1b;
        k_xw2<<<dim3(782, 8), 256, 0, stream>>>(layer ? (const void*)h1 : x, Wf2, xwb,
                                                sbuf, tbuf,
                                                layer ? flags + 1 : flags, layer);
        k_attn<<<12500, 256, 0, stream>>>(rowptr, elist, ei, et, sbuf, tbuf, xwb,
                                          b, lg, lb,
                                          layer ? h1 : (const float*)nullptr,
                                          layer ? hsum : h1, flags);
    }
    // decode weight swizzle into xwb space (xwb dead after attn L1)
    k_dswz<<<17, 256, 0, stream>>>(mw1, mw2, Wf, flags);
    k_decode2<<<3125, 256, 0, stream>>>(hsum, edges, Wf, mb1, mb2, d_out, flags);
}